// Round 5
// baseline (983.929 us; speedup 1.0000x reference)
//
#include <hip/hip_runtime.h>

#define N_NODES 100000
#define N_EDGES 1600000
#define EPSV 1e-5f

// ---------------- CSR-by-destination build ----------------

__global__ void hist_kernel(const int* __restrict__ ei, int* __restrict__ cnt) {
  int e = blockIdx.x * blockDim.x + threadIdx.x;
  if (e >= N_EDGES) return;
  atomicAdd(&cnt[ei[N_EDGES + e]], 1);
}

#define SCAN_BLK 1024
#define SCAN_NB ((N_NODES + SCAN_BLK - 1) / SCAN_BLK)  // 98

__global__ void scan_phase1(const int* __restrict__ cnt, int* __restrict__ blocksum) {
  __shared__ int part[256];
  int base = blockIdx.x * SCAN_BLK + threadIdx.x * 4;
  int s = 0;
#pragma unroll
  for (int i = 0; i < 4; ++i) {
    int idx = base + i;
    if (idx < N_NODES) s += cnt[idx];
  }
  part[threadIdx.x] = s;
  __syncthreads();
  for (int d = 128; d > 0; d >>= 1) {
    if (threadIdx.x < d) part[threadIdx.x] += part[threadIdx.x + d];
    __syncthreads();
  }
  if (threadIdx.x == 0) blocksum[blockIdx.x] = part[0];
}

__global__ void scan_phase2(int* __restrict__ blocksum, int* __restrict__ rowptr) {
  __shared__ int part[128];
  int tid = threadIdx.x;
  int v = (tid < SCAN_NB) ? blocksum[tid] : 0;
  part[tid] = v;
  __syncthreads();
  for (int d = 1; d < 128; d <<= 1) {
    int t = (tid >= d) ? part[tid - d] : 0;
    __syncthreads();
    part[tid] += t;
    __syncthreads();
  }
  if (tid < SCAN_NB) blocksum[tid] = part[tid] - v;  // exclusive
  if (tid == 127) rowptr[N_NODES] = part[127];
}

__global__ void scan_phase3(const int* __restrict__ cnt, const int* __restrict__ blocksum,
                            int* __restrict__ rowptr, int* __restrict__ cursor) {
  __shared__ int part[256];
  int base = blockIdx.x * SCAN_BLK + threadIdx.x * 4;
  int c[4];
  int s = 0;
#pragma unroll
  for (int i = 0; i < 4; ++i) {
    int idx = base + i;
    c[i] = (idx < N_NODES) ? cnt[idx] : 0;
    s += c[i];
  }
  part[threadIdx.x] = s;
  __syncthreads();
  int me = s;
  for (int d = 1; d < 256; d <<= 1) {
    int t = (threadIdx.x >= d) ? part[threadIdx.x - d] : 0;
    __syncthreads();
    part[threadIdx.x] += t;
    __syncthreads();
  }
  int off = blocksum[blockIdx.x] + part[threadIdx.x] - me;
#pragma unroll
  for (int i = 0; i < 4; ++i) {
    int idx = base + i;
    if (idx < N_NODES) {
      rowptr[idx] = off;
      cursor[idx] = off;
      off += c[i];
    }
  }
}

// packed fill: one 8B store per edge (src, weight-bits)
__global__ void fill_kernel(const int* __restrict__ ei, const float* __restrict__ ew,
                            int* __restrict__ cursor, int2* __restrict__ col) {
  int e = blockIdx.x * blockDim.x + threadIdx.x;
  if (e >= N_EDGES) return;
  int d = ei[N_EDGES + e];
  int p = atomicAdd(&cursor[d], 1);
  col[p] = make_int2(ei[e], __float_as_int(ew[e]));
}

// ---------------- gather-side segment sums ----------------

__global__ void gather_d32(const float* __restrict__ x, const int* __restrict__ rowptr,
                           const int2* __restrict__ col, float* __restrict__ agg) {
  int gid = blockIdx.x * blockDim.x + threadIdx.x;
  int n = gid >> 3;
  if (n >= N_NODES) return;
  int c = gid & 7;
  int beg = rowptr[n], end = rowptr[n + 1];
  float4 acc = make_float4(0.f, 0.f, 0.f, 0.f);
  for (int p = beg; p < end; ++p) {
    int src = col[p].x;
    float4 v = *reinterpret_cast<const float4*>(x + (size_t)src * 32 + c * 4);
    acc.x += v.x; acc.y += v.y; acc.z += v.z; acc.w += v.w;
  }
  *reinterpret_cast<float4*>(agg + (size_t)n * 32 + c * 4) = acc;
}

template <bool WEIGHTED>
__global__ void gather_d64(const float* __restrict__ h, const int* __restrict__ rowptr,
                           const int2* __restrict__ col, float* __restrict__ agg) {
  int gid = blockIdx.x * blockDim.x + threadIdx.x;
  int n = gid >> 4;
  if (n >= N_NODES) return;
  int c = gid & 15;
  int beg = rowptr[n], end = rowptr[n + 1];
  float4 acc = make_float4(0.f, 0.f, 0.f, 0.f);
  for (int p = beg; p < end; ++p) {
    int2 ce = col[p];
    float4 v = *reinterpret_cast<const float4*>(h + (size_t)ce.x * 64 + c * 4);
    if (WEIGHTED) {
      float w = __int_as_float(ce.y);
      acc.x = fmaf(v.x, w, acc.x); acc.y = fmaf(v.y, w, acc.y);
      acc.z = fmaf(v.z, w, acc.z); acc.w = fmaf(v.w, w, acc.w);
    } else {
      acc.x += v.x; acc.y += v.y; acc.z += v.z; acc.w += v.w;
    }
  }
  *reinterpret_cast<float4*>(agg + (size_t)n * 64 + c * 4) = acc;
}

// ---------------- LDS-tiled node GEMM with fused BN partial stats ----------------
// out[M x DO] = [A1 | A2] @ [W1 ; W2]^T
// MODE 0: plain.  MODE 1: += R.  MODE 2: BN+relu A1 while staging (also write h2act).
// STATS: per-block column {sum, sumsq} -> partials[blk * 2*DO ...]

template <int K1, int K2, int DO, int MODE, int STATS>
__global__ __launch_bounds__(256) void gemm_node(
    const float* __restrict__ A1, const float* __restrict__ A2,
    const float* __restrict__ W1, const float* __restrict__ W2,
    const float* __restrict__ sc, const float* __restrict__ sh,
    const float* __restrict__ R, float* __restrict__ out,
    float* h2act, float* __restrict__ partials) {
  constexpr int K = K1 + K2;
  constexpr int NC = K / 64;
  constexpr int NJB = DO / 64;
  __shared__ __align__(16) float A_lds[64][68];
  __shared__ __align__(16) float W_lds[64][DO + 4];

  const int tid = threadIdx.x;
  const int tx = tid & 15, ty = tid >> 4;
  const int nbase = blockIdx.x * 64;

  float4 acc[4][NJB];
#pragma unroll
  for (int i = 0; i < 4; ++i)
#pragma unroll
    for (int jb = 0; jb < NJB; ++jb) acc[i][jb] = make_float4(0.f, 0.f, 0.f, 0.f);

#pragma unroll 1
  for (int c = 0; c < NC; ++c) {
    const int kb = c * 64;
    if (c) __syncthreads();
#pragma unroll
    for (int it = 0; it < 4; ++it) {
      int idx = it * 256 + tid;
      int nl = idx >> 4;
      int kq = (idx & 15) * 4;
      int k = kb + kq;
      int ng = nbase + nl;
      float4 v = make_float4(0.f, 0.f, 0.f, 0.f);
      if (ng < N_NODES) {
        if (K2 == 0 || k < K1)
          v = *reinterpret_cast<const float4*>(A1 + (size_t)ng * K1 + k);
        else
          v = *reinterpret_cast<const float4*>(A2 + (size_t)ng * K2 + (k - K1));
      }
      if (MODE == 2) {
        float4 s4 = *reinterpret_cast<const float4*>(sc + k);
        float4 h4 = *reinterpret_cast<const float4*>(sh + k);
        v.x = fmaxf(fmaf(v.x, s4.x, h4.x), 0.f);
        v.y = fmaxf(fmaf(v.y, s4.y, h4.y), 0.f);
        v.z = fmaxf(fmaf(v.z, s4.z, h4.z), 0.f);
        v.w = fmaxf(fmaf(v.w, s4.w, h4.w), 0.f);
        if (ng < N_NODES)
          *reinterpret_cast<float4*>(h2act + (size_t)ng * K1 + k) = v;
      }
      *reinterpret_cast<float4*>(&A_lds[nl][kq]) = v;
    }
#pragma unroll
    for (int it = 0; it < DO / 4; ++it) {
      int idx = it * 256 + tid;
      int j = idx >> 6;
      int kl = idx & 63;
      int k = kb + kl;
      float w;
      if (K2 == 0 || k < K1) w = W1[(size_t)j * K1 + k];
      else w = W2[(size_t)j * K2 + (k - K1)];
      W_lds[kl][j] = w;
    }
    __syncthreads();
#pragma unroll 4
    for (int k4 = 0; k4 < 16; ++k4) {
      float4 a[4];
#pragma unroll
      for (int i = 0; i < 4; ++i)
        a[i] = *reinterpret_cast<const float4*>(&A_lds[ty * 4 + i][k4 * 4]);
#pragma unroll
      for (int q = 0; q < 4; ++q) {
#pragma unroll
        for (int jb = 0; jb < NJB; ++jb) {
          float4 w = *reinterpret_cast<const float4*>(&W_lds[k4 * 4 + q][jb * 64 + tx * 4]);
#pragma unroll
          for (int i = 0; i < 4; ++i) {
            float av = reinterpret_cast<const float*>(&a[i])[q];
            acc[i][jb].x = fmaf(av, w.x, acc[i][jb].x);
            acc[i][jb].y = fmaf(av, w.y, acc[i][jb].y);
            acc[i][jb].z = fmaf(av, w.z, acc[i][jb].z);
            acc[i][jb].w = fmaf(av, w.w, acc[i][jb].w);
          }
        }
      }
    }
  }
  // ---- R add (into acc so stats see it) + output ----
#pragma unroll
  for (int i = 0; i < 4; ++i) {
    int ng = nbase + ty * 4 + i;
    if (ng >= N_NODES) continue;
#pragma unroll
    for (int jb = 0; jb < NJB; ++jb) {
      if (MODE == 1) {
        float4 rr = *reinterpret_cast<const float4*>(R + (size_t)ng * DO + jb * 64 + tx * 4);
        acc[i][jb].x += rr.x; acc[i][jb].y += rr.y;
        acc[i][jb].z += rr.z; acc[i][jb].w += rr.w;
      }
      *reinterpret_cast<float4*>(out + (size_t)ng * DO + jb * 64 + tx * 4) = acc[i][jb];
    }
  }
  // ---- fused BN partial stats ----
  if (STATS) {
    __syncthreads();  // done reading A_lds/W_lds; safe to reuse
    float* sums_l = &A_lds[0][0];  // [16][DO]
    float* sq_l = &W_lds[0][0];    // [16][DO]
#pragma unroll
    for (int jb = 0; jb < NJB; ++jb) {
      float4 s = make_float4(0.f, 0.f, 0.f, 0.f);
      float4 q = make_float4(0.f, 0.f, 0.f, 0.f);
#pragma unroll
      for (int i = 0; i < 4; ++i) {
        if (nbase + ty * 4 + i < N_NODES) {
          float4 v = acc[i][jb];
          s.x += v.x; s.y += v.y; s.z += v.z; s.w += v.w;
          q.x = fmaf(v.x, v.x, q.x); q.y = fmaf(v.y, v.y, q.y);
          q.z = fmaf(v.z, v.z, q.z); q.w = fmaf(v.w, v.w, q.w);
        }
      }
      *reinterpret_cast<float4*>(&sums_l[ty * DO + jb * 64 + tx * 4]) = s;
      *reinterpret_cast<float4*>(&sq_l[ty * DO + jb * 64 + tx * 4]) = q;
    }
    __syncthreads();
    if (tid < DO) {
      float s = 0.f, q = 0.f;
#pragma unroll
      for (int t = 0; t < 16; ++t) {
        s += sums_l[t * DO + tid];
        q += sq_l[t * DO + tid];
      }
      partials[(size_t)blockIdx.x * (2 * DO) + tid] = s;
      partials[(size_t)blockIdx.x * (2 * DO) + DO + tid] = q;
    }
  }
}

// ---------------- BN partial reduce + finalize ----------------

template <int D>
__global__ void bn_reduce(const float* __restrict__ partials, int nblk,
                          const float* __restrict__ g, const float* __restrict__ be,
                          float* __restrict__ sc, float* __restrict__ sh) {
  __shared__ float s_lds[256], q_lds[256];
  constexpr int P = 256 / D;
  int f = threadIdx.x % D;
  int part = threadIdx.x / D;
  float s = 0.f, q = 0.f;
  for (int b = part; b < nblk; b += P) {
    s += partials[(size_t)b * 2 * D + f];
    q += partials[(size_t)b * 2 * D + D + f];
  }
  s_lds[threadIdx.x] = s;
  q_lds[threadIdx.x] = q;
  __syncthreads();
  if (threadIdx.x < D) {
#pragma unroll
    for (int t = 1; t < P; ++t) {
      s += s_lds[t * D + f];
      q += q_lds[t * D + f];
    }
    const float invN = 1.f / (float)N_NODES;
    float mean = s * invN;
    float var = q * invN - mean * mean;
    float r = rsqrtf(var + EPSV);
    float scale = g[f] * r;
    sc[f] = scale;
    sh[f] = be[f] - mean * scale;
  }
}

__global__ void bn_apply_relu_d64(const float* __restrict__ hp, const float* __restrict__ sc,
                                  const float* __restrict__ sh, float* __restrict__ h) {
  long long i4 = (long long)blockIdx.x * blockDim.x + threadIdx.x;
  if (i4 * 4 >= (long long)N_NODES * 64) return;
  int j0 = (int)((i4 * 4) & 63);
  float4 v = reinterpret_cast<const float4*>(hp)[i4];
  v.x = fmaxf(fmaf(v.x, sc[j0 + 0], sh[j0 + 0]), 0.f);
  v.y = fmaxf(fmaf(v.y, sc[j0 + 1], sh[j0 + 1]), 0.f);
  v.z = fmaxf(fmaf(v.z, sc[j0 + 2], sh[j0 + 2]), 0.f);
  v.w = fmaxf(fmaf(v.w, sc[j0 + 3], sh[j0 + 3]), 0.f);
  reinterpret_cast<float4*>(h)[i4] = v;
}

// ---------------- fused residual + classifier ----------------

__global__ __launch_bounds__(256) void final_fused(
    const float* __restrict__ h3p, const float* __restrict__ h1,
    const float* __restrict__ sc, const float* __restrict__ sh,
    const float* __restrict__ Wc1, const float* __restrict__ bc1,
    const float* __restrict__ Wc2, const float* __restrict__ bc2,
    float* __restrict__ out) {
  __shared__ __align__(16) float t_lds[64][68];
  __shared__ __align__(16) float w1_lds[64][36];
  __shared__ __align__(16) float c_lds[64][36];
  __shared__ __align__(16) float w2_lds[64];
  __shared__ __align__(16) float b1_lds[32];
  __shared__ float b2_lds[2];
  const int tid = threadIdx.x;
  const int nbase = blockIdx.x * 64;

#pragma unroll
  for (int it = 0; it < 4; ++it) {
    int idx = it * 256 + tid;
    int nl = idx >> 4;
    int k = (idx & 15) * 4;
    int ng = nbase + nl;
    float4 v = make_float4(0.f, 0.f, 0.f, 0.f);
    if (ng < N_NODES) {
      float4 p = *reinterpret_cast<const float4*>(h3p + (size_t)ng * 64 + k);
      float4 u = *reinterpret_cast<const float4*>(h1 + (size_t)ng * 64 + k);
      float4 s4 = *reinterpret_cast<const float4*>(sc + k);
      float4 h4 = *reinterpret_cast<const float4*>(sh + k);
      v.x = fmaxf(fmaf(p.x, s4.x, h4.x) + u.x, 0.f);
      v.y = fmaxf(fmaf(p.y, s4.y, h4.y) + u.y, 0.f);
      v.z = fmaxf(fmaf(p.z, s4.z, h4.z) + u.z, 0.f);
      v.w = fmaxf(fmaf(p.w, s4.w, h4.w) + u.w, 0.f);
    }
    *reinterpret_cast<float4*>(&t_lds[nl][k]) = v;
  }
#pragma unroll
  for (int it = 0; it < 8; ++it) {
    int idx = it * 256 + tid;
    int j = idx >> 6;
    int k = idx & 63;
    w1_lds[k][j] = Wc1[(size_t)j * 64 + k];
  }
  if (tid < 64) w2_lds[tid] = Wc2[tid];
  else if (tid < 96) b1_lds[tid - 64] = bc1[tid - 64];
  else if (tid < 98) b2_lds[tid - 96] = bc2[tid - 96];
  __syncthreads();

  {
    const int tx = tid & 7, ty = tid >> 3;
    float4 a0c = make_float4(0.f, 0.f, 0.f, 0.f);
    float4 a1c = make_float4(0.f, 0.f, 0.f, 0.f);
#pragma unroll 4
    for (int k4 = 0; k4 < 16; ++k4) {
      float4 a0 = *reinterpret_cast<const float4*>(&t_lds[ty * 2 + 0][k4 * 4]);
      float4 a1 = *reinterpret_cast<const float4*>(&t_lds[ty * 2 + 1][k4 * 4]);
#pragma unroll
      for (int q = 0; q < 4; ++q) {
        float4 w = *reinterpret_cast<const float4*>(&w1_lds[k4 * 4 + q][tx * 4]);
        float a0q = reinterpret_cast<const float*>(&a0)[q];
        float a1q = reinterpret_cast<const float*>(&a1)[q];
        a0c.x = fmaf(a0q, w.x, a0c.x); a0c.y = fmaf(a0q, w.y, a0c.y);
        a0c.z = fmaf(a0q, w.z, a0c.z); a0c.w = fmaf(a0q, w.w, a0c.w);
        a1c.x = fmaf(a1q, w.x, a1c.x); a1c.y = fmaf(a1q, w.y, a1c.y);
        a1c.z = fmaf(a1q, w.z, a1c.z); a1c.w = fmaf(a1q, w.w, a1c.w);
      }
    }
    float4 b = *reinterpret_cast<const float4*>(&b1_lds[tx * 4]);
    a0c.x = fmaxf(a0c.x + b.x, 0.f); a0c.y = fmaxf(a0c.y + b.y, 0.f);
    a0c.z = fmaxf(a0c.z + b.z, 0.f); a0c.w = fmaxf(a0c.w + b.w, 0.f);
    a1c.x = fmaxf(a1c.x + b.x, 0.f); a1c.y = fmaxf(a1c.y + b.y, 0.f);
    a1c.z = fmaxf(a1c.z + b.z, 0.f); a1c.w = fmaxf(a1c.w + b.w, 0.f);
    *reinterpret_cast<float4*>(&c_lds[ty * 2 + 0][tx * 4]) = a0c;
    *reinterpret_cast<float4*>(&c_lds[ty * 2 + 1][tx * 4]) = a1c;
  }
  __syncthreads();

  if (tid < 128) {
    int nl = tid >> 1, o = tid & 1;
    int ng = nbase + nl;
    if (ng < N_NODES) {
      float s = b2_lds[o];
#pragma unroll
      for (int k = 0; k < 32; ++k) s = fmaf(c_lds[nl][k], w2_lds[o * 32 + k], s);
      out[(size_t)ng * 2 + o] = s;
    }
  }
}

// ---------------- launcher ----------------

extern "C" void kernel_launch(void* const* d_in, const int* in_sizes, int n_in,
                              void* d_out, int out_size, void* d_ws, size_t ws_size,
                              hipStream_t stream) {
  const float* x      = (const float*)d_in[0];
  const int*   ei     = (const int*)d_in[1];
  const float* ew     = (const float*)d_in[2];
  const float* W1rel  = (const float*)d_in[3];
  const float* W1root = (const float*)d_in[5];
  const float* W2rel  = (const float*)d_in[6];
  const float* W2root = (const float*)d_in[8];
  const float* W3rel  = (const float*)d_in[9];
  const float* W3root = (const float*)d_in[11];
  const float* g1  = (const float*)d_in[12];
  const float* be1 = (const float*)d_in[13];
  const float* g2  = (const float*)d_in[14];
  const float* be2 = (const float*)d_in[15];
  const float* g3  = (const float*)d_in[16];
  const float* be3 = (const float*)d_in[17];
  const float* Wc1 = (const float*)d_in[18];
  const float* bc1 = (const float*)d_in[19];
  const float* Wc2 = (const float*)d_in[20];
  const float* bc2 = (const float*)d_in[21];

  float* ws = (float*)d_ws;
  const size_t NF = (size_t)N_NODES * 64;
  float* A = ws;            // agg1 (N*32) -> agg2 (N*64) -> agg3 (N*64)
  float* B = ws + NF;       // h1pre -> y2 -> h3pre
  float* C = ws + 2 * NF;   // h1, live to the end
  float* E = ws + 3 * NF;   // h2pre / h2act in place (N*128)
  float* X = ws + 5 * NF;
  float* S = X;                                // 1024 floats: sc/sh slots
  int* rowptr   = (int*)(X + 1024);            // N+2
  int* cnt      = rowptr + (N_NODES + 2);      // N
  int* cursor   = cnt + N_NODES;               // N
  int* blocksum = cursor + N_NODES;            // 128
  int2* col     = (int2*)(blocksum + 128);     // E packed (src, w)
  float* partials = (float*)(col + N_EDGES);   // tileBlocks * 256
  // S: sc1@128 sh1@192 | sc2@512 sh2@640 | sc3@896 sh3@960

  hipMemsetAsync(cnt, 0, N_NODES * sizeof(int), stream);

  const int edgeBlocks = (N_EDGES + 255) / 256;
  const int tileBlocks = (N_NODES + 63) / 64;  // 1563

  // CSR build (by destination)
  hist_kernel<<<edgeBlocks, 256, 0, stream>>>(ei, cnt);
  scan_phase1<<<SCAN_NB, 256, 0, stream>>>(cnt, blocksum);
  scan_phase2<<<1, 128, 0, stream>>>(blocksum, rowptr);
  scan_phase3<<<SCAN_NB, 256, 0, stream>>>(cnt, blocksum, rowptr, cursor);
  fill_kernel<<<edgeBlocks, 256, 0, stream>>>(ei, ew, cursor, col);

  // ---- layer 1 ----
  gather_d32<<<(N_NODES * 8 + 255) / 256, 256, 0, stream>>>(x, rowptr, col, A);
  gemm_node<32, 32, 64, 0, 1><<<tileBlocks, 256, 0, stream>>>(
      A, x, W1rel, W1root, nullptr, nullptr, nullptr, B, nullptr, partials);
  bn_reduce<64><<<1, 256, 0, stream>>>(partials, tileBlocks, g1, be1, S + 128, S + 192);
  bn_apply_relu_d64<<<(int)((NF / 4 + 255) / 256), 256, 0, stream>>>(B, S + 128, S + 192, C);

  // ---- layer 2 ----
  gather_d64<false><<<(N_NODES * 16 + 255) / 256, 256, 0, stream>>>(C, rowptr, col, A);
  gemm_node<64, 64, 128, 0, 1><<<tileBlocks, 256, 0, stream>>>(
      A, C, W2rel, W2root, nullptr, nullptr, nullptr, E, nullptr, partials);
  bn_reduce<128><<<1, 256, 0, stream>>>(partials, tileBlocks, g2, be2, S + 512, S + 640);
  gemm_node<128, 0, 64, 2, 0><<<tileBlocks, 256, 0, stream>>>(
      E, nullptr, W3rel, nullptr, S + 512, S + 640, nullptr, B, E, nullptr);

  // ---- layer 3 ----
  gather_d64<true><<<(N_NODES * 16 + 255) / 256, 256, 0, stream>>>(B, rowptr, col, A);
  gemm_node<128, 0, 64, 1, 1><<<tileBlocks, 256, 0, stream>>>(
      E, nullptr, W3root, nullptr, nullptr, nullptr, A, B, nullptr, partials);
  bn_reduce<64><<<1, 256, 0, stream>>>(partials, tileBlocks, g3, be3, S + 896, S + 960);

  // ---- residual + classifier ----
  final_fused<<<tileBlocks, 256, 0, stream>>>(B, C, S + 896, S + 960, Wc1, bc1, Wc2, bc2,
                                              (float*)d_out);
}

// Round 6
// 655.119 us; speedup vs baseline: 1.5019x; 1.5019x over previous
//
#include <hip/hip_runtime.h>

#define N_NODES 100000
#define N_EDGES 1600000
#define EPSV 1e-5f

// ---------------- CSR-by-destination build ----------------

__global__ void hist_kernel(const int* __restrict__ ei, int* __restrict__ cnt) {
  int e = blockIdx.x * blockDim.x + threadIdx.x;
  if (e >= N_EDGES) return;
  atomicAdd(&cnt[ei[N_EDGES + e]], 1);
}

#define SCAN_BLK 1024
#define SCAN_NB ((N_NODES + SCAN_BLK - 1) / SCAN_BLK)  // 98

__global__ void scan_phase1(const int* __restrict__ cnt, int* __restrict__ blocksum) {
  __shared__ int part[256];
  int base = blockIdx.x * SCAN_BLK + threadIdx.x * 4;
  int s = 0;
#pragma unroll
  for (int i = 0; i < 4; ++i) {
    int idx = base + i;
    if (idx < N_NODES) s += cnt[idx];
  }
  part[threadIdx.x] = s;
  __syncthreads();
  for (int d = 128; d > 0; d >>= 1) {
    if (threadIdx.x < d) part[threadIdx.x] += part[threadIdx.x + d];
    __syncthreads();
  }
  if (threadIdx.x == 0) blocksum[blockIdx.x] = part[0];
}

__global__ void scan_phase2(int* __restrict__ blocksum, int* __restrict__ rowptr) {
  __shared__ int part[128];
  int tid = threadIdx.x;
  int v = (tid < SCAN_NB) ? blocksum[tid] : 0;
  part[tid] = v;
  __syncthreads();
  for (int d = 1; d < 128; d <<= 1) {
    int t = (tid >= d) ? part[tid - d] : 0;
    __syncthreads();
    part[tid] += t;
    __syncthreads();
  }
  if (tid < SCAN_NB) blocksum[tid] = part[tid] - v;  // exclusive
  if (tid == 127) rowptr[N_NODES] = part[127];
}

__global__ void scan_phase3(const int* __restrict__ cnt, const int* __restrict__ blocksum,
                            int* __restrict__ rowptr, int* __restrict__ cursor) {
  __shared__ int part[256];
  int base = blockIdx.x * SCAN_BLK + threadIdx.x * 4;
  int c[4];
  int s = 0;
#pragma unroll
  for (int i = 0; i < 4; ++i) {
    int idx = base + i;
    c[i] = (idx < N_NODES) ? cnt[idx] : 0;
    s += c[i];
  }
  part[threadIdx.x] = s;
  __syncthreads();
  int me = s;
  for (int d = 1; d < 256; d <<= 1) {
    int t = (threadIdx.x >= d) ? part[threadIdx.x - d] : 0;
    __syncthreads();
    part[threadIdx.x] += t;
    __syncthreads();
  }
  int off = blocksum[blockIdx.x] + part[threadIdx.x] - me;
#pragma unroll
  for (int i = 0; i < 4; ++i) {
    int idx = base + i;
    if (idx < N_NODES) {
      rowptr[idx] = off;
      cursor[idx] = off;
      off += c[i];
    }
  }
}

// packed fill: one 8B store per edge (src, weight-bits)
__global__ void fill_kernel(const int* __restrict__ ei, const float* __restrict__ ew,
                            int* __restrict__ cursor, int2* __restrict__ col) {
  int e = blockIdx.x * blockDim.x + threadIdx.x;
  if (e >= N_EDGES) return;
  int d = ei[N_EDGES + e];
  int p = atomicAdd(&cursor[d], 1);
  col[p] = make_int2(ei[e], __float_as_int(ew[e]));
}

// ---------------- gather-side segment sums ----------------

__global__ void gather_d32(const float* __restrict__ x, const int* __restrict__ rowptr,
                           const int2* __restrict__ col, float* __restrict__ agg) {
  int gid = blockIdx.x * blockDim.x + threadIdx.x;
  int n = gid >> 3;
  if (n >= N_NODES) return;
  int c = gid & 7;
  int beg = rowptr[n], end = rowptr[n + 1];
  float4 acc = make_float4(0.f, 0.f, 0.f, 0.f);
  for (int p = beg; p < end; ++p) {
    int src = col[p].x;
    float4 v = *reinterpret_cast<const float4*>(x + (size_t)src * 32 + c * 4);
    acc.x += v.x; acc.y += v.y; acc.z += v.z; acc.w += v.w;
  }
  *reinterpret_cast<float4*>(agg + (size_t)n * 32 + c * 4) = acc;
}

template <bool WEIGHTED>
__global__ void gather_d64(const float* __restrict__ h, const int* __restrict__ rowptr,
                           const int2* __restrict__ col, float* __restrict__ agg) {
  int gid = blockIdx.x * blockDim.x + threadIdx.x;
  int n = gid >> 4;
  if (n >= N_NODES) return;
  int c = gid & 15;
  int beg = rowptr[n], end = rowptr[n + 1];
  float4 acc = make_float4(0.f, 0.f, 0.f, 0.f);
  for (int p = beg; p < end; ++p) {
    int2 ce = col[p];
    float4 v = *reinterpret_cast<const float4*>(h + (size_t)ce.x * 64 + c * 4);
    if (WEIGHTED) {
      float w = __int_as_float(ce.y);
      acc.x = fmaf(v.x, w, acc.x); acc.y = fmaf(v.y, w, acc.y);
      acc.z = fmaf(v.z, w, acc.z); acc.w = fmaf(v.w, w, acc.w);
    } else {
      acc.x += v.x; acc.y += v.y; acc.z += v.z; acc.w += v.w;
    }
  }
  *reinterpret_cast<float4*>(agg + (size_t)n * 64 + c * 4) = acc;
}

// ---------------- LDS-tiled node GEMM with fused BN stats (atomic) ----------------
// out[M x DO] = [A1 | A2] @ [W1 ; W2]^T
// MODE 0: plain.  MODE 1: += R.  MODE 2: BN+relu A1 while staging (also write h2act).
// STATS: per-block column {sum, sumsq} atomically added into sums[2*DO]

template <int K1, int K2, int DO, int MODE, int STATS>
__global__ __launch_bounds__(256) void gemm_node(
    const float* __restrict__ A1, const float* __restrict__ A2,
    const float* __restrict__ W1, const float* __restrict__ W2,
    const float* __restrict__ sc, const float* __restrict__ sh,
    const float* __restrict__ R, float* __restrict__ out,
    float* h2act, float* __restrict__ sums) {
  constexpr int K = K1 + K2;
  constexpr int NC = K / 64;
  constexpr int NJB = DO / 64;
  __shared__ __align__(16) float A_lds[64][68];
  __shared__ __align__(16) float W_lds[64][DO + 4];

  const int tid = threadIdx.x;
  const int tx = tid & 15, ty = tid >> 4;
  const int nbase = blockIdx.x * 64;

  float4 acc[4][NJB];
#pragma unroll
  for (int i = 0; i < 4; ++i)
#pragma unroll
    for (int jb = 0; jb < NJB; ++jb) acc[i][jb] = make_float4(0.f, 0.f, 0.f, 0.f);

#pragma unroll 1
  for (int c = 0; c < NC; ++c) {
    const int kb = c * 64;
    if (c) __syncthreads();
#pragma unroll
    for (int it = 0; it < 4; ++it) {
      int idx = it * 256 + tid;
      int nl = idx >> 4;
      int kq = (idx & 15) * 4;
      int k = kb + kq;
      int ng = nbase + nl;
      float4 v = make_float4(0.f, 0.f, 0.f, 0.f);
      if (ng < N_NODES) {
        if (K2 == 0 || k < K1)
          v = *reinterpret_cast<const float4*>(A1 + (size_t)ng * K1 + k);
        else
          v = *reinterpret_cast<const float4*>(A2 + (size_t)ng * K2 + (k - K1));
      }
      if (MODE == 2) {
        float4 s4 = *reinterpret_cast<const float4*>(sc + k);
        float4 h4 = *reinterpret_cast<const float4*>(sh + k);
        v.x = fmaxf(fmaf(v.x, s4.x, h4.x), 0.f);
        v.y = fmaxf(fmaf(v.y, s4.y, h4.y), 0.f);
        v.z = fmaxf(fmaf(v.z, s4.z, h4.z), 0.f);
        v.w = fmaxf(fmaf(v.w, s4.w, h4.w), 0.f);
        if (ng < N_NODES)
          *reinterpret_cast<float4*>(h2act + (size_t)ng * K1 + k) = v;
      }
      *reinterpret_cast<float4*>(&A_lds[nl][kq]) = v;
    }
#pragma unroll
    for (int it = 0; it < DO / 4; ++it) {
      int idx = it * 256 + tid;
      int j = idx >> 6;
      int kl = idx & 63;
      int k = kb + kl;
      float w;
      if (K2 == 0 || k < K1) w = W1[(size_t)j * K1 + k];
      else w = W2[(size_t)j * K2 + (k - K1)];
      W_lds[kl][j] = w;
    }
    __syncthreads();
#pragma unroll 4
    for (int k4 = 0; k4 < 16; ++k4) {
      float4 a[4];
#pragma unroll
      for (int i = 0; i < 4; ++i)
        a[i] = *reinterpret_cast<const float4*>(&A_lds[ty * 4 + i][k4 * 4]);
#pragma unroll
      for (int q = 0; q < 4; ++q) {
#pragma unroll
        for (int jb = 0; jb < NJB; ++jb) {
          float4 w = *reinterpret_cast<const float4*>(&W_lds[k4 * 4 + q][jb * 64 + tx * 4]);
#pragma unroll
          for (int i = 0; i < 4; ++i) {
            float av = reinterpret_cast<const float*>(&a[i])[q];
            acc[i][jb].x = fmaf(av, w.x, acc[i][jb].x);
            acc[i][jb].y = fmaf(av, w.y, acc[i][jb].y);
            acc[i][jb].z = fmaf(av, w.z, acc[i][jb].z);
            acc[i][jb].w = fmaf(av, w.w, acc[i][jb].w);
          }
        }
      }
    }
  }
  // ---- R add (into acc so stats see it) + output ----
#pragma unroll
  for (int i = 0; i < 4; ++i) {
    int ng = nbase + ty * 4 + i;
    if (ng >= N_NODES) continue;
#pragma unroll
    for (int jb = 0; jb < NJB; ++jb) {
      if (MODE == 1) {
        float4 rr = *reinterpret_cast<const float4*>(R + (size_t)ng * DO + jb * 64 + tx * 4);
        acc[i][jb].x += rr.x; acc[i][jb].y += rr.y;
        acc[i][jb].z += rr.z; acc[i][jb].w += rr.w;
      }
      *reinterpret_cast<float4*>(out + (size_t)ng * DO + jb * 64 + tx * 4) = acc[i][jb];
    }
  }
  // ---- fused BN stats: block-local LDS reduce, then one atomic per column ----
  if (STATS) {
    __syncthreads();  // done reading A_lds/W_lds; safe to reuse
    float* sums_l = &A_lds[0][0];  // [16][DO]
    float* sq_l = &W_lds[0][0];    // [16][DO]
#pragma unroll
    for (int jb = 0; jb < NJB; ++jb) {
      float4 s = make_float4(0.f, 0.f, 0.f, 0.f);
      float4 q = make_float4(0.f, 0.f, 0.f, 0.f);
#pragma unroll
      for (int i = 0; i < 4; ++i) {
        if (nbase + ty * 4 + i < N_NODES) {
          float4 v = acc[i][jb];
          s.x += v.x; s.y += v.y; s.z += v.z; s.w += v.w;
          q.x = fmaf(v.x, v.x, q.x); q.y = fmaf(v.y, v.y, q.y);
          q.z = fmaf(v.z, v.z, q.z); q.w = fmaf(v.w, v.w, q.w);
        }
      }
      *reinterpret_cast<float4*>(&sums_l[ty * DO + jb * 64 + tx * 4]) = s;
      *reinterpret_cast<float4*>(&sq_l[ty * DO + jb * 64 + tx * 4]) = q;
    }
    __syncthreads();
    if (tid < DO) {
      float s = 0.f, q = 0.f;
#pragma unroll
      for (int t = 0; t < 16; ++t) {
        s += sums_l[t * DO + tid];
        q += sq_l[t * DO + tid];
      }
      unsafeAtomicAdd(&sums[tid], s);
      unsafeAtomicAdd(&sums[DO + tid], q);
    }
  }
}

// ---------------- BN finalize ----------------

__global__ void bn_finalize(const float* __restrict__ sums, const float* __restrict__ g,
                            const float* __restrict__ be, float* __restrict__ sc,
                            float* __restrict__ sh, int D) {
  int j = threadIdx.x;
  if (j >= D) return;
  const float invN = 1.f / (float)N_NODES;
  float mean = sums[j] * invN;
  float var = sums[D + j] * invN - mean * mean;
  float r = rsqrtf(var + EPSV);
  float scale = g[j] * r;
  sc[j] = scale;
  sh[j] = be[j] - mean * scale;
}

__global__ void bn_apply_relu_d64(const float* __restrict__ hp, const float* __restrict__ sc,
                                  const float* __restrict__ sh, float* __restrict__ h) {
  long long i4 = (long long)blockIdx.x * blockDim.x + threadIdx.x;
  if (i4 * 4 >= (long long)N_NODES * 64) return;
  int j0 = (int)((i4 * 4) & 63);
  float4 v = reinterpret_cast<const float4*>(hp)[i4];
  v.x = fmaxf(fmaf(v.x, sc[j0 + 0], sh[j0 + 0]), 0.f);
  v.y = fmaxf(fmaf(v.y, sc[j0 + 1], sh[j0 + 1]), 0.f);
  v.z = fmaxf(fmaf(v.z, sc[j0 + 2], sh[j0 + 2]), 0.f);
  v.w = fmaxf(fmaf(v.w, sc[j0 + 3], sh[j0 + 3]), 0.f);
  reinterpret_cast<float4*>(h)[i4] = v;
}

// ---------------- fused residual + classifier ----------------

__global__ __launch_bounds__(256) void final_fused(
    const float* __restrict__ h3p, const float* __restrict__ h1,
    const float* __restrict__ sc, const float* __restrict__ sh,
    const float* __restrict__ Wc1, const float* __restrict__ bc1,
    const float* __restrict__ Wc2, const float* __restrict__ bc2,
    float* __restrict__ out) {
  __shared__ __align__(16) float t_lds[64][68];
  __shared__ __align__(16) float w1_lds[64][36];
  __shared__ __align__(16) float c_lds[64][36];
  __shared__ __align__(16) float w2_lds[64];
  __shared__ __align__(16) float b1_lds[32];
  __shared__ float b2_lds[2];
  const int tid = threadIdx.x;
  const int nbase = blockIdx.x * 64;

#pragma unroll
  for (int it = 0; it < 4; ++it) {
    int idx = it * 256 + tid;
    int nl = idx >> 4;
    int k = (idx & 15) * 4;
    int ng = nbase + nl;
    float4 v = make_float4(0.f, 0.f, 0.f, 0.f);
    if (ng < N_NODES) {
      float4 p = *reinterpret_cast<const float4*>(h3p + (size_t)ng * 64 + k);
      float4 u = *reinterpret_cast<const float4*>(h1 + (size_t)ng * 64 + k);
      float4 s4 = *reinterpret_cast<const float4*>(sc + k);
      float4 h4 = *reinterpret_cast<const float4*>(sh + k);
      v.x = fmaxf(fmaf(p.x, s4.x, h4.x) + u.x, 0.f);
      v.y = fmaxf(fmaf(p.y, s4.y, h4.y) + u.y, 0.f);
      v.z = fmaxf(fmaf(p.z, s4.z, h4.z) + u.z, 0.f);
      v.w = fmaxf(fmaf(p.w, s4.w, h4.w) + u.w, 0.f);
    }
    *reinterpret_cast<float4*>(&t_lds[nl][k]) = v;
  }
#pragma unroll
  for (int it = 0; it < 8; ++it) {
    int idx = it * 256 + tid;
    int j = idx >> 6;
    int k = idx & 63;
    w1_lds[k][j] = Wc1[(size_t)j * 64 + k];
  }
  if (tid < 64) w2_lds[tid] = Wc2[tid];
  else if (tid < 96) b1_lds[tid - 64] = bc1[tid - 64];
  else if (tid < 98) b2_lds[tid - 96] = bc2[tid - 96];
  __syncthreads();

  {
    const int tx = tid & 7, ty = tid >> 3;
    float4 a0c = make_float4(0.f, 0.f, 0.f, 0.f);
    float4 a1c = make_float4(0.f, 0.f, 0.f, 0.f);
#pragma unroll 4
    for (int k4 = 0; k4 < 16; ++k4) {
      float4 a0 = *reinterpret_cast<const float4*>(&t_lds[ty * 2 + 0][k4 * 4]);
      float4 a1 = *reinterpret_cast<const float4*>(&t_lds[ty * 2 + 1][k4 * 4]);
#pragma unroll
      for (int q = 0; q < 4; ++q) {
        float4 w = *reinterpret_cast<const float4*>(&w1_lds[k4 * 4 + q][tx * 4]);
        float a0q = reinterpret_cast<const float*>(&a0)[q];
        float a1q = reinterpret_cast<const float*>(&a1)[q];
        a0c.x = fmaf(a0q, w.x, a0c.x); a0c.y = fmaf(a0q, w.y, a0c.y);
        a0c.z = fmaf(a0q, w.z, a0c.z); a0c.w = fmaf(a0q, w.w, a0c.w);
        a1c.x = fmaf(a1q, w.x, a1c.x); a1c.y = fmaf(a1q, w.y, a1c.y);
        a1c.z = fmaf(a1q, w.z, a1c.z); a1c.w = fmaf(a1q, w.w, a1c.w);
      }
    }
    float4 b = *reinterpret_cast<const float4*>(&b1_lds[tx * 4]);
    a0c.x = fmaxf(a0c.x + b.x, 0.f); a0c.y = fmaxf(a0c.y + b.y, 0.f);
    a0c.z = fmaxf(a0c.z + b.z, 0.f); a0c.w = fmaxf(a0c.w + b.w, 0.f);
    a1c.x = fmaxf(a1c.x + b.x, 0.f); a1c.y = fmaxf(a1c.y + b.y, 0.f);
    a1c.z = fmaxf(a1c.z + b.z, 0.f); a1c.w = fmaxf(a1c.w + b.w, 0.f);
    *reinterpret_cast<float4*>(&c_lds[ty * 2 + 0][tx * 4]) = a0c;
    *reinterpret_cast<float4*>(&c_lds[ty * 2 + 1][tx * 4]) = a1c;
  }
  __syncthreads();

  if (tid < 128) {
    int nl = tid >> 1, o = tid & 1;
    int ng = nbase + nl;
    if (ng < N_NODES) {
      float s = b2_lds[o];
#pragma unroll
      for (int k = 0; k < 32; ++k) s = fmaf(c_lds[nl][k], w2_lds[o * 32 + k], s);
      out[(size_t)ng * 2 + o] = s;
    }
  }
}

// ---------------- launcher ----------------

extern "C" void kernel_launch(void* const* d_in, const int* in_sizes, int n_in,
                              void* d_out, int out_size, void* d_ws, size_t ws_size,
                              hipStream_t stream) {
  const float* x      = (const float*)d_in[0];
  const int*   ei     = (const int*)d_in[1];
  const float* ew     = (const float*)d_in[2];
  const float* W1rel  = (const float*)d_in[3];
  const float* W1root = (const float*)d_in[5];
  const float* W2rel  = (const float*)d_in[6];
  const float* W2root = (const float*)d_in[8];
  const float* W3rel  = (const float*)d_in[9];
  const float* W3root = (const float*)d_in[11];
  const float* g1  = (const float*)d_in[12];
  const float* be1 = (const float*)d_in[13];
  const float* g2  = (const float*)d_in[14];
  const float* be2 = (const float*)d_in[15];
  const float* g3  = (const float*)d_in[16];
  const float* be3 = (const float*)d_in[17];
  const float* Wc1 = (const float*)d_in[18];
  const float* bc1 = (const float*)d_in[19];
  const float* Wc2 = (const float*)d_in[20];
  const float* bc2 = (const float*)d_in[21];

  float* ws = (float*)d_ws;
  const size_t NF = (size_t)N_NODES * 64;
  float* A = ws;            // agg1 (N*32) -> agg2 (N*64) -> agg3 (N*64)
  float* B = ws + NF;       // h1pre -> y2 -> h3pre
  float* C = ws + 2 * NF;   // h1, live to the end
  float* E = ws + 3 * NF;   // h2pre / h2act in place (N*128)
  float* X = ws + 5 * NF;
  float* S = X;                                // 1024 floats: sums + sc/sh slots
  int* rowptr   = (int*)(X + 1024);            // N+2
  int* cnt      = rowptr + (N_NODES + 2);      // N
  int* cursor   = cnt + N_NODES;               // N
  int* blocksum = cursor + N_NODES;            // 128
  int2* col     = (int2*)(blocksum + 128);     // E packed (src, w)
  // S: sums1@0(128) sc1@128 sh1@192 | sums2@256(256) sc2@512 sh2@640 |
  //    sums3@768(128) sc3@896 sh3@960

  hipMemsetAsync(S, 0, 1024 * sizeof(float), stream);
  hipMemsetAsync(cnt, 0, N_NODES * sizeof(int), stream);

  const int edgeBlocks = (N_EDGES + 255) / 256;
  const int tileBlocks = (N_NODES + 63) / 64;  // 1563

  // CSR build (by destination)
  hist_kernel<<<edgeBlocks, 256, 0, stream>>>(ei, cnt);
  scan_phase1<<<SCAN_NB, 256, 0, stream>>>(cnt, blocksum);
  scan_phase2<<<1, 128, 0, stream>>>(blocksum, rowptr);
  scan_phase3<<<SCAN_NB, 256, 0, stream>>>(cnt, blocksum, rowptr, cursor);
  fill_kernel<<<edgeBlocks, 256, 0, stream>>>(ei, ew, cursor, col);

  // ---- layer 1 ----
  gather_d32<<<(N_NODES * 8 + 255) / 256, 256, 0, stream>>>(x, rowptr, col, A);
  gemm_node<32, 32, 64, 0, 1><<<tileBlocks, 256, 0, stream>>>(
      A, x, W1rel, W1root, nullptr, nullptr, nullptr, B, nullptr, S);
  bn_finalize<<<1, 128, 0, stream>>>(S, g1, be1, S + 128, S + 192, 64);
  bn_apply_relu_d64<<<(int)((NF / 4 + 255) / 256), 256, 0, stream>>>(B, S + 128, S + 192, C);

  // ---- layer 2 ----
  gather_d64<false><<<(N_NODES * 16 + 255) / 256, 256, 0, stream>>>(C, rowptr, col, A);
  gemm_node<64, 64, 128, 0, 1><<<tileBlocks, 256, 0, stream>>>(
      A, C, W2rel, W2root, nullptr, nullptr, nullptr, E, nullptr, S + 256);
  bn_finalize<<<1, 128, 0, stream>>>(S + 256, g2, be2, S + 512, S + 640, 128);
  gemm_node<128, 0, 64, 2, 0><<<tileBlocks, 256, 0, stream>>>(
      E, nullptr, W3rel, nullptr, S + 512, S + 640, nullptr, B, E, nullptr);

  // ---- layer 3 ----
  gather_d64<true><<<(N_NODES * 16 + 255) / 256, 256, 0, stream>>>(B, rowptr, col, A);
  gemm_node<128, 0, 64, 1, 1><<<tileBlocks, 256, 0, stream>>>(
      E, nullptr, W3root, nullptr, nullptr, nullptr, A, B, nullptr, S + 768);
  bn_finalize<<<1, 128, 0, stream>>>(S + 768, g3, be3, S + 896, S + 960, 64);

  // ---- residual + classifier ----
  final_fused<<<tileBlocks, 256, 0, stream>>>(B, C, S + 896, S + 960, Wc1, bc1, Wc2, bc2,
                                              (float*)d_out);
}

// Round 7
// 634.225 us; speedup vs baseline: 1.5514x; 1.0329x over previous
//
#include <hip/hip_runtime.h>

#define N_NODES 100000
#define N_EDGES 1600000
#define EPSV 1e-5f

__device__ __forceinline__ ushort f2bf(float f) {
  unsigned u = __float_as_uint(f);
  unsigned r = (u + 0x7FFFu + ((u >> 16) & 1u)) >> 16;
  return (ushort)r;
}
__device__ __forceinline__ float bf2f(ushort u) {
  return __uint_as_float((unsigned)u << 16);
}

// ---------------- CSR-by-destination build ----------------

__global__ void hist_kernel(const int* __restrict__ ei, int* __restrict__ cnt) {
  int e = blockIdx.x * blockDim.x + threadIdx.x;
  if (e >= N_EDGES) return;
  atomicAdd(&cnt[ei[N_EDGES + e]], 1);
}

#define SCAN_BLK 1024
#define SCAN_NB ((N_NODES + SCAN_BLK - 1) / SCAN_BLK)  // 98

__global__ void scan_phase1(const int* __restrict__ cnt, int* __restrict__ blocksum) {
  __shared__ int part[256];
  int base = blockIdx.x * SCAN_BLK + threadIdx.x * 4;
  int s = 0;
#pragma unroll
  for (int i = 0; i < 4; ++i) {
    int idx = base + i;
    if (idx < N_NODES) s += cnt[idx];
  }
  part[threadIdx.x] = s;
  __syncthreads();
  for (int d = 128; d > 0; d >>= 1) {
    if (threadIdx.x < d) part[threadIdx.x] += part[threadIdx.x + d];
    __syncthreads();
  }
  if (threadIdx.x == 0) blocksum[blockIdx.x] = part[0];
}

__global__ void scan_phase2(int* __restrict__ blocksum, int* __restrict__ rowptr) {
  __shared__ int part[128];
  int tid = threadIdx.x;
  int v = (tid < SCAN_NB) ? blocksum[tid] : 0;
  part[tid] = v;
  __syncthreads();
  for (int d = 1; d < 128; d <<= 1) {
    int t = (tid >= d) ? part[tid - d] : 0;
    __syncthreads();
    part[tid] += t;
    __syncthreads();
  }
  if (tid < SCAN_NB) blocksum[tid] = part[tid] - v;  // exclusive
  if (tid == 127) rowptr[N_NODES] = part[127];
}

__global__ void scan_phase3(const int* __restrict__ cnt, const int* __restrict__ blocksum,
                            int* __restrict__ rowptr, int* __restrict__ cursor) {
  __shared__ int part[256];
  int base = blockIdx.x * SCAN_BLK + threadIdx.x * 4;
  int c[4];
  int s = 0;
#pragma unroll
  for (int i = 0; i < 4; ++i) {
    int idx = base + i;
    c[i] = (idx < N_NODES) ? cnt[idx] : 0;
    s += c[i];
  }
  part[threadIdx.x] = s;
  __syncthreads();
  int me = s;
  for (int d = 1; d < 256; d <<= 1) {
    int t = (threadIdx.x >= d) ? part[threadIdx.x - d] : 0;
    __syncthreads();
    part[threadIdx.x] += t;
    __syncthreads();
  }
  int off = blocksum[blockIdx.x] + part[threadIdx.x] - me;
#pragma unroll
  for (int i = 0; i < 4; ++i) {
    int idx = base + i;
    if (idx < N_NODES) {
      rowptr[idx] = off;
      cursor[idx] = off;
      off += c[i];
    }
  }
}

// packed fill: one 8B store per edge (src, weight-bits)
__global__ void fill_kernel(const int* __restrict__ ei, const float* __restrict__ ew,
                            int* __restrict__ cursor, int2* __restrict__ col) {
  int e = blockIdx.x * blockDim.x + threadIdx.x;
  if (e >= N_EDGES) return;
  int d = ei[N_EDGES + e];
  int p = atomicAdd(&cursor[d], 1);
  col[p] = make_int2(ei[e], __float_as_int(ew[e]));
}

// ---------------- fp32 -> bf16 cast ----------------

__global__ void cast_bf16(const float* __restrict__ in, ushort* __restrict__ out, int n4) {
  int i = blockIdx.x * blockDim.x + threadIdx.x;
  if (i >= n4) return;
  float4 v = reinterpret_cast<const float4*>(in)[i];
  ushort4 o = make_ushort4(f2bf(v.x), f2bf(v.y), f2bf(v.z), f2bf(v.w));
  reinterpret_cast<ushort4*>(out)[i] = o;
}

// ---------------- gather-side segment sums (bf16 rows, fp32 accum) ----------------

__global__ void gather_d32_bf(const ushort* __restrict__ xb, const int* __restrict__ rowptr,
                              const int2* __restrict__ col, float* __restrict__ agg) {
  int gid = blockIdx.x * blockDim.x + threadIdx.x;
  int n = gid >> 3;
  if (n >= N_NODES) return;
  int c = gid & 7;
  int beg = rowptr[n], end = rowptr[n + 1];
  float4 acc = make_float4(0.f, 0.f, 0.f, 0.f);
  for (int p = beg; p < end; ++p) {
    int src = col[p].x;
    ushort4 u = *reinterpret_cast<const ushort4*>(xb + (size_t)src * 32 + c * 4);
    acc.x += bf2f(u.x); acc.y += bf2f(u.y); acc.z += bf2f(u.z); acc.w += bf2f(u.w);
  }
  *reinterpret_cast<float4*>(agg + (size_t)n * 32 + c * 4) = acc;
}

template <bool WEIGHTED>
__global__ void gather_d64_bf(const ushort* __restrict__ hb, const int* __restrict__ rowptr,
                              const int2* __restrict__ col, float* __restrict__ agg) {
  int gid = blockIdx.x * blockDim.x + threadIdx.x;
  int n = gid >> 4;
  if (n >= N_NODES) return;
  int c = gid & 15;
  int beg = rowptr[n], end = rowptr[n + 1];
  float4 acc = make_float4(0.f, 0.f, 0.f, 0.f);
  for (int p = beg; p < end; ++p) {
    int2 ce = col[p];
    ushort4 u = *reinterpret_cast<const ushort4*>(hb + (size_t)ce.x * 64 + c * 4);
    float vx = bf2f(u.x), vy = bf2f(u.y), vz = bf2f(u.z), vw = bf2f(u.w);
    if (WEIGHTED) {
      float w = __int_as_float(ce.y);
      acc.x = fmaf(vx, w, acc.x); acc.y = fmaf(vy, w, acc.y);
      acc.z = fmaf(vz, w, acc.z); acc.w = fmaf(vw, w, acc.w);
    } else {
      acc.x += vx; acc.y += vy; acc.z += vz; acc.w += vw;
    }
  }
  *reinterpret_cast<float4*>(agg + (size_t)n * 64 + c * 4) = acc;
}

// ---------------- LDS-tiled node GEMM with fused BN stats (atomic) ----------------
// out[M x DO] = [A1 | A2] @ [W1 ; W2]^T
// MODE 0: plain.  MODE 1: += R.  MODE 2: BN+relu A1 while staging (also write h2act).
// STATS: per-block column {sum, sumsq} atomically added into sums[2*DO]
// OUTB16: write output as bf16 (used for y2, consumed only by the gather)

template <int K1, int K2, int DO, int MODE, int STATS, int OUTB16>
__global__ __launch_bounds__(256) void gemm_node(
    const float* __restrict__ A1, const float* __restrict__ A2,
    const float* __restrict__ W1, const float* __restrict__ W2,
    const float* __restrict__ sc, const float* __restrict__ sh,
    const float* __restrict__ R, float* __restrict__ out,
    float* h2act, float* __restrict__ sums) {
  constexpr int K = K1 + K2;
  constexpr int NC = K / 64;
  constexpr int NJB = DO / 64;
  __shared__ __align__(16) float A_lds[64][68];
  __shared__ __align__(16) float W_lds[64][DO + 4];

  const int tid = threadIdx.x;
  const int tx = tid & 15, ty = tid >> 4;
  const int nbase = blockIdx.x * 64;

  float4 acc[4][NJB];
#pragma unroll
  for (int i = 0; i < 4; ++i)
#pragma unroll
    for (int jb = 0; jb < NJB; ++jb) acc[i][jb] = make_float4(0.f, 0.f, 0.f, 0.f);

#pragma unroll 1
  for (int c = 0; c < NC; ++c) {
    const int kb = c * 64;
    if (c) __syncthreads();
#pragma unroll
    for (int it = 0; it < 4; ++it) {
      int idx = it * 256 + tid;
      int nl = idx >> 4;
      int kq = (idx & 15) * 4;
      int k = kb + kq;
      int ng = nbase + nl;
      float4 v = make_float4(0.f, 0.f, 0.f, 0.f);
      if (ng < N_NODES) {
        if (K2 == 0 || k < K1)
          v = *reinterpret_cast<const float4*>(A1 + (size_t)ng * K1 + k);
        else
          v = *reinterpret_cast<const float4*>(A2 + (size_t)ng * K2 + (k - K1));
      }
      if (MODE == 2) {
        float4 s4 = *reinterpret_cast<const float4*>(sc + k);
        float4 h4 = *reinterpret_cast<const float4*>(sh + k);
        v.x = fmaxf(fmaf(v.x, s4.x, h4.x), 0.f);
        v.y = fmaxf(fmaf(v.y, s4.y, h4.y), 0.f);
        v.z = fmaxf(fmaf(v.z, s4.z, h4.z), 0.f);
        v.w = fmaxf(fmaf(v.w, s4.w, h4.w), 0.f);
        if (ng < N_NODES)
          *reinterpret_cast<float4*>(h2act + (size_t)ng * K1 + k) = v;
      }
      *reinterpret_cast<float4*>(&A_lds[nl][kq]) = v;
    }
#pragma unroll
    for (int it = 0; it < DO / 4; ++it) {
      int idx = it * 256 + tid;
      int j = idx >> 6;
      int kl = idx & 63;
      int k = kb + kl;
      float w;
      if (K2 == 0 || k < K1) w = W1[(size_t)j * K1 + k];
      else w = W2[(size_t)j * K2 + (k - K1)];
      W_lds[kl][j] = w;
    }
    __syncthreads();
#pragma unroll 4
    for (int k4 = 0; k4 < 16; ++k4) {
      float4 a[4];
#pragma unroll
      for (int i = 0; i < 4; ++i)
        a[i] = *reinterpret_cast<const float4*>(&A_lds[ty * 4 + i][k4 * 4]);
#pragma unroll
      for (int q = 0; q < 4; ++q) {
#pragma unroll
        for (int jb = 0; jb < NJB; ++jb) {
          float4 w = *reinterpret_cast<const float4*>(&W_lds[k4 * 4 + q][jb * 64 + tx * 4]);
#pragma unroll
          for (int i = 0; i < 4; ++i) {
            float av = reinterpret_cast<const float*>(&a[i])[q];
            acc[i][jb].x = fmaf(av, w.x, acc[i][jb].x);
            acc[i][jb].y = fmaf(av, w.y, acc[i][jb].y);
            acc[i][jb].z = fmaf(av, w.z, acc[i][jb].z);
            acc[i][jb].w = fmaf(av, w.w, acc[i][jb].w);
          }
        }
      }
    }
  }
  // ---- R add (into acc so stats see it) + output ----
#pragma unroll
  for (int i = 0; i < 4; ++i) {
    int ng = nbase + ty * 4 + i;
    if (ng >= N_NODES) continue;
#pragma unroll
    for (int jb = 0; jb < NJB; ++jb) {
      if (MODE == 1) {
        float4 rr = *reinterpret_cast<const float4*>(R + (size_t)ng * DO + jb * 64 + tx * 4);
        acc[i][jb].x += rr.x; acc[i][jb].y += rr.y;
        acc[i][jb].z += rr.z; acc[i][jb].w += rr.w;
      }
      if (OUTB16) {
        ushort4 o = make_ushort4(f2bf(acc[i][jb].x), f2bf(acc[i][jb].y),
                                 f2bf(acc[i][jb].z), f2bf(acc[i][jb].w));
        *reinterpret_cast<ushort4*>((ushort*)out + (size_t)ng * DO + jb * 64 + tx * 4) = o;
      } else {
        *reinterpret_cast<float4*>(out + (size_t)ng * DO + jb * 64 + tx * 4) = acc[i][jb];
      }
    }
  }
  // ---- fused BN stats: block-local LDS reduce, then one atomic per column ----
  if (STATS) {
    __syncthreads();  // done reading A_lds/W_lds; safe to reuse
    float* sums_l = &A_lds[0][0];  // [16][DO]
    float* sq_l = &W_lds[0][0];    // [16][DO]
#pragma unroll
    for (int jb = 0; jb < NJB; ++jb) {
      float4 s = make_float4(0.f, 0.f, 0.f, 0.f);
      float4 q = make_float4(0.f, 0.f, 0.f, 0.f);
#pragma unroll
      for (int i = 0; i < 4; ++i) {
        if (nbase + ty * 4 + i < N_NODES) {
          float4 v = acc[i][jb];
          s.x += v.x; s.y += v.y; s.z += v.z; s.w += v.w;
          q.x = fmaf(v.x, v.x, q.x); q.y = fmaf(v.y, v.y, q.y);
          q.z = fmaf(v.z, v.z, q.z); q.w = fmaf(v.w, v.w, q.w);
        }
      }
      *reinterpret_cast<float4*>(&sums_l[ty * DO + jb * 64 + tx * 4]) = s;
      *reinterpret_cast<float4*>(&sq_l[ty * DO + jb * 64 + tx * 4]) = q;
    }
    __syncthreads();
    if (tid < DO) {
      float s = 0.f, q = 0.f;
#pragma unroll
      for (int t = 0; t < 16; ++t) {
        s += sums_l[t * DO + tid];
        q += sq_l[t * DO + tid];
      }
      unsafeAtomicAdd(&sums[tid], s);
      unsafeAtomicAdd(&sums[DO + tid], q);
    }
  }
}

// ---------------- BN finalize ----------------

__global__ void bn_finalize(const float* __restrict__ sums, const float* __restrict__ g,
                            const float* __restrict__ be, float* __restrict__ sc,
                            float* __restrict__ sh, int D) {
  int j = threadIdx.x;
  if (j >= D) return;
  const float invN = 1.f / (float)N_NODES;
  float mean = sums[j] * invN;
  float var = sums[D + j] * invN - mean * mean;
  float r = rsqrtf(var + EPSV);
  float scale = g[j] * r;
  sc[j] = scale;
  sh[j] = be[j] - mean * scale;
}

// h1 = relu(bn1(h1pre)) (fp32) + bf16 copy for the gather
__global__ void bn_apply_relu_d64(const float* __restrict__ hp, const float* __restrict__ sc,
                                  const float* __restrict__ sh, float* __restrict__ h,
                                  ushort* __restrict__ hb) {
  long long i4 = (long long)blockIdx.x * blockDim.x + threadIdx.x;
  if (i4 * 4 >= (long long)N_NODES * 64) return;
  int j0 = (int)((i4 * 4) & 63);
  float4 v = reinterpret_cast<const float4*>(hp)[i4];
  v.x = fmaxf(fmaf(v.x, sc[j0 + 0], sh[j0 + 0]), 0.f);
  v.y = fmaxf(fmaf(v.y, sc[j0 + 1], sh[j0 + 1]), 0.f);
  v.z = fmaxf(fmaf(v.z, sc[j0 + 2], sh[j0 + 2]), 0.f);
  v.w = fmaxf(fmaf(v.w, sc[j0 + 3], sh[j0 + 3]), 0.f);
  reinterpret_cast<float4*>(h)[i4] = v;
  ushort4 o = make_ushort4(f2bf(v.x), f2bf(v.y), f2bf(v.z), f2bf(v.w));
  reinterpret_cast<ushort4*>(hb)[i4] = o;
}

// ---------------- fused residual + classifier ----------------

__global__ __launch_bounds__(256) void final_fused(
    const float* __restrict__ h3p, const float* __restrict__ h1,
    const float* __restrict__ sc, const float* __restrict__ sh,
    const float* __restrict__ Wc1, const float* __restrict__ bc1,
    const float* __restrict__ Wc2, const float* __restrict__ bc2,
    float* __restrict__ out) {
  __shared__ __align__(16) float t_lds[64][68];
  __shared__ __align__(16) float w1_lds[64][36];
  __shared__ __align__(16) float c_lds[64][36];
  __shared__ __align__(16) float w2_lds[64];
  __shared__ __align__(16) float b1_lds[32];
  __shared__ float b2_lds[2];
  const int tid = threadIdx.x;
  const int nbase = blockIdx.x * 64;

#pragma unroll
  for (int it = 0; it < 4; ++it) {
    int idx = it * 256 + tid;
    int nl = idx >> 4;
    int k = (idx & 15) * 4;
    int ng = nbase + nl;
    float4 v = make_float4(0.f, 0.f, 0.f, 0.f);
    if (ng < N_NODES) {
      float4 p = *reinterpret_cast<const float4*>(h3p + (size_t)ng * 64 + k);
      float4 u = *reinterpret_cast<const float4*>(h1 + (size_t)ng * 64 + k);
      float4 s4 = *reinterpret_cast<const float4*>(sc + k);
      float4 h4 = *reinterpret_cast<const float4*>(sh + k);
      v.x = fmaxf(fmaf(p.x, s4.x, h4.x) + u.x, 0.f);
      v.y = fmaxf(fmaf(p.y, s4.y, h4.y) + u.y, 0.f);
      v.z = fmaxf(fmaf(p.z, s4.z, h4.z) + u.z, 0.f);
      v.w = fmaxf(fmaf(p.w, s4.w, h4.w) + u.w, 0.f);
    }
    *reinterpret_cast<float4*>(&t_lds[nl][k]) = v;
  }
#pragma unroll
  for (int it = 0; it < 8; ++it) {
    int idx = it * 256 + tid;
    int j = idx >> 6;
    int k = idx & 63;
    w1_lds[k][j] = Wc1[(size_t)j * 64 + k];
  }
  if (tid < 64) w2_lds[tid] = Wc2[tid];
  else if (tid < 96) b1_lds[tid - 64] = bc1[tid - 64];
  else if (tid < 98) b2_lds[tid - 96] = bc2[tid - 96];
  __syncthreads();

  {
    const int tx = tid & 7, ty = tid >> 3;
    float4 a0c = make_float4(0.f, 0.f, 0.f, 0.f);
    float4 a1c = make_float4(0.f, 0.f, 0.f, 0.f);
#pragma unroll 4
    for (int k4 = 0; k4 < 16; ++k4) {
      float4 a0 = *reinterpret_cast<const float4*>(&t_lds[ty * 2 + 0][k4 * 4]);
      float4 a1 = *reinterpret_cast<const float4*>(&t_lds[ty * 2 + 1][k4 * 4]);
#pragma unroll
      for (int q = 0; q < 4; ++q) {
        float4 w = *reinterpret_cast<const float4*>(&w1_lds[k4 * 4 + q][tx * 4]);
        float a0q = reinterpret_cast<const float*>(&a0)[q];
        float a1q = reinterpret_cast<const float*>(&a1)[q];
        a0c.x = fmaf(a0q, w.x, a0c.x); a0c.y = fmaf(a0q, w.y, a0c.y);
        a0c.z = fmaf(a0q, w.z, a0c.z); a0c.w = fmaf(a0q, w.w, a0c.w);
        a1c.x = fmaf(a1q, w.x, a1c.x); a1c.y = fmaf(a1q, w.y, a1c.y);
        a1c.z = fmaf(a1q, w.z, a1c.z); a1c.w = fmaf(a1q, w.w, a1c.w);
      }
    }
    float4 b = *reinterpret_cast<const float4*>(&b1_lds[tx * 4]);
    a0c.x = fmaxf(a0c.x + b.x, 0.f); a0c.y = fmaxf(a0c.y + b.y, 0.f);
    a0c.z = fmaxf(a0c.z + b.z, 0.f); a0c.w = fmaxf(a0c.w + b.w, 0.f);
    a1c.x = fmaxf(a1c.x + b.x, 0.f); a1c.y = fmaxf(a1c.y + b.y, 0.f);
    a1c.z = fmaxf(a1c.z + b.z, 0.f); a1c.w = fmaxf(a1c.w + b.w, 0.f);
    *reinterpret_cast<float4*>(&c_lds[ty * 2 + 0][tx * 4]) = a0c;
    *reinterpret_cast<float4*>(&c_lds[ty * 2 + 1][tx * 4]) = a1c;
  }
  __syncthreads();

  if (tid < 128) {
    int nl = tid >> 1, o = tid & 1;
    int ng = nbase + nl;
    if (ng < N_NODES) {
      float s = b2_lds[o];
#pragma unroll
      for (int k = 0; k < 32; ++k) s = fmaf(c_lds[nl][k], w2_lds[o * 32 + k], s);
      out[(size_t)ng * 2 + o] = s;
    }
  }
}

// ---------------- launcher ----------------

extern "C" void kernel_launch(void* const* d_in, const int* in_sizes, int n_in,
                              void* d_out, int out_size, void* d_ws, size_t ws_size,
                              hipStream_t stream) {
  const float* x      = (const float*)d_in[0];
  const int*   ei     = (const int*)d_in[1];
  const float* ew     = (const float*)d_in[2];
  const float* W1rel  = (const float*)d_in[3];
  const float* W1root = (const float*)d_in[5];
  const float* W2rel  = (const float*)d_in[6];
  const float* W2root = (const float*)d_in[8];
  const float* W3rel  = (const float*)d_in[9];
  const float* W3root = (const float*)d_in[11];
  const float* g1  = (const float*)d_in[12];
  const float* be1 = (const float*)d_in[13];
  const float* g2  = (const float*)d_in[14];
  const float* be2 = (const float*)d_in[15];
  const float* g3  = (const float*)d_in[16];
  const float* be3 = (const float*)d_in[17];
  const float* Wc1 = (const float*)d_in[18];
  const float* bc1 = (const float*)d_in[19];
  const float* Wc2 = (const float*)d_in[20];
  const float* bc2 = (const float*)d_in[21];

  float* ws = (float*)d_ws;
  const size_t NF = (size_t)N_NODES * 64;
  float* A = ws;            // agg1 (N*32) -> agg2 (N*64) -> agg3 (N*64)
  float* B = ws + NF;       // xb(bf16) -> h1pre -> y2b(bf16) -> h3pre
  float* C = ws + 2 * NF;   // h1 fp32, live to the end
  float* E = ws + 3 * NF;   // h1b(bf16) -> h2pre / h2act in place (N*128)
  float* X = ws + 5 * NF;
  float* S = X;                                // 1024 floats: sums + sc/sh slots
  int* rowptr   = (int*)(X + 1024);            // N+2
  int* cnt      = rowptr + (N_NODES + 2);      // N
  int* cursor   = cnt + N_NODES;               // N
  int* blocksum = cursor + N_NODES;            // 128
  int2* col     = (int2*)(blocksum + 128);     // E packed (src, w)
  // S: sums1@0(128) sc1@128 sh1@192 | sums2@256(256) sc2@512 sh2@640 |
  //    sums3@768(128) sc3@896 sh3@960

  ushort* xb  = (ushort*)B;  // N*32 bf16, dead before h1pre written
  ushort* h1b = (ushort*)E;  // N*64 bf16, dead before h2pre written
  ushort* y2b = (ushort*)B;  // N*64 bf16, dead before h3pre written

  hipMemsetAsync(S, 0, 1024 * sizeof(float), stream);
  hipMemsetAsync(cnt, 0, N_NODES * sizeof(int), stream);

  const int edgeBlocks = (N_EDGES + 255) / 256;
  const int tileBlocks = (N_NODES + 63) / 64;  // 1563

  // x -> bf16 (independent of CSR build)
  cast_bf16<<<(N_NODES * 32 / 4 + 255) / 256, 256, 0, stream>>>(x, xb, N_NODES * 32 / 4);

  // CSR build (by destination)
  hist_kernel<<<edgeBlocks, 256, 0, stream>>>(ei, cnt);
  scan_phase1<<<SCAN_NB, 256, 0, stream>>>(cnt, blocksum);
  scan_phase2<<<1, 128, 0, stream>>>(blocksum, rowptr);
  scan_phase3<<<SCAN_NB, 256, 0, stream>>>(cnt, blocksum, rowptr, cursor);
  fill_kernel<<<edgeBlocks, 256, 0, stream>>>(ei, ew, cursor, col);

  // ---- layer 1 ----
  gather_d32_bf<<<(N_NODES * 8 + 255) / 256, 256, 0, stream>>>(xb, rowptr, col, A);
  gemm_node<32, 32, 64, 0, 1, 0><<<tileBlocks, 256, 0, stream>>>(
      A, x, W1rel, W1root, nullptr, nullptr, nullptr, B, nullptr, S);
  bn_finalize<<<1, 128, 0, stream>>>(S, g1, be1, S + 128, S + 192, 64);
  bn_apply_relu_d64<<<(int)((NF / 4 + 255) / 256), 256, 0, stream>>>(B, S + 128, S + 192, C,
                                                                     h1b);

  // ---- layer 2 ----
  gather_d64_bf<false><<<(N_NODES * 16 + 255) / 256, 256, 0, stream>>>(h1b, rowptr, col, A);
  gemm_node<64, 64, 128, 0, 1, 0><<<tileBlocks, 256, 0, stream>>>(
      A, C, W2rel, W2root, nullptr, nullptr, nullptr, E, nullptr, S + 256);
  bn_finalize<<<1, 128, 0, stream>>>(S + 256, g2, be2, S + 512, S + 640, 128);
  // y2b = bf16( relu(bn2(h2pre)) @ W3rel^T ); h2act -> E in place
  gemm_node<128, 0, 64, 2, 0, 1><<<tileBlocks, 256, 0, stream>>>(
      E, nullptr, W3rel, nullptr, S + 512, S + 640, nullptr, (float*)y2b, E, nullptr);

  // ---- layer 3 ----
  gather_d64_bf<true><<<(N_NODES * 16 + 255) / 256, 256, 0, stream>>>(y2b, rowptr, col, A);
  gemm_node<128, 0, 64, 1, 1, 0><<<tileBlocks, 256, 0, stream>>>(
      E, nullptr, W3root, nullptr, nullptr, nullptr, A, B, nullptr, S + 768);
  bn_finalize<<<1, 128, 0, stream>>>(S + 768, g3, be3, S + 896, S + 960, 64);

  // ---- residual + classifier ----
  final_fused<<<tileBlocks, 256, 0, stream>>>(B, C, S + 896, S + 960, Wc1, bc1, Wc2, bc2,
                                              (float*)d_out);
}

// Round 8
// 612.038 us; speedup vs baseline: 1.6076x; 1.0363x over previous
//
#include <hip/hip_runtime.h>

#define N_NODES 100000
#define N_EDGES 1600000
#define EPSV 1e-5f

__device__ __forceinline__ ushort f2bf(float f) {
  unsigned u = __float_as_uint(f);
  unsigned r = (u + 0x7FFFu + ((u >> 16) & 1u)) >> 16;
  return (ushort)r;
}

// ---------------- CSR-by-destination build ----------------

__global__ void hist_kernel(const int* __restrict__ ei, int* __restrict__ cnt) {
  int e = blockIdx.x * blockDim.x + threadIdx.x;
  if (e >= N_EDGES) return;
  atomicAdd(&cnt[ei[N_EDGES + e]], 1);
}

#define SCAN_BLK 1024
#define SCAN_NB ((N_NODES + SCAN_BLK - 1) / SCAN_BLK)  // 98

__global__ void scan_phase1(const int* __restrict__ cnt, int* __restrict__ blocksum) {
  __shared__ int part[256];
  int base = blockIdx.x * SCAN_BLK + threadIdx.x * 4;
  int s = 0;
#pragma unroll
  for (int i = 0; i < 4; ++i) {
    int idx = base + i;
    if (idx < N_NODES) s += cnt[idx];
  }
  part[threadIdx.x] = s;
  __syncthreads();
  for (int d = 128; d > 0; d >>= 1) {
    if (threadIdx.x < d) part[threadIdx.x] += part[threadIdx.x + d];
    __syncthreads();
  }
  if (threadIdx.x == 0) blocksum[blockIdx.x] = part[0];
}

__global__ void scan_phase2(int* __restrict__ blocksum, int* __restrict__ rowptr) {
  __shared__ int part[128];
  int tid = threadIdx.x;
  int v = (tid < SCAN_NB) ? blocksum[tid] : 0;
  part[tid] = v;
  __syncthreads();
  for (int d = 1; d < 128; d <<= 1) {
    int t = (tid >= d) ? part[tid - d] : 0;
    __syncthreads();
    part[tid] += t;
    __syncthreads();
  }
  if (tid < SCAN_NB) blocksum[tid] = part[tid] - v;  // exclusive
  if (tid == 127) rowptr[N_NODES] = part[127];
}

__global__ void scan_phase3(const int* __restrict__ cnt, const int* __restrict__ blocksum,
                            int* __restrict__ rowptr, int* __restrict__ cursor) {
  __shared__ int part[256];
  int base = blockIdx.x * SCAN_BLK + threadIdx.x * 4;
  int c[4];
  int s = 0;
#pragma unroll
  for (int i = 0; i < 4; ++i) {
    int idx = base + i;
    c[i] = (idx < N_NODES) ? cnt[idx] : 0;
    s += c[i];
  }
  part[threadIdx.x] = s;
  __syncthreads();
  int me = s;
  for (int d = 1; d < 256; d <<= 1) {
    int t = (threadIdx.x >= d) ? part[threadIdx.x - d] : 0;
    __syncthreads();
    part[threadIdx.x] += t;
    __syncthreads();
  }
  int off = blocksum[blockIdx.x] + part[threadIdx.x] - me;
#pragma unroll
  for (int i = 0; i < 4; ++i) {
    int idx = base + i;
    if (idx < N_NODES) {
      rowptr[idx] = off;
      cursor[idx] = off;
      off += c[i];
    }
  }
}

// packed fill: one nontemporal 8B store per edge (src | wbits)
__global__ void fill_kernel(const int* __restrict__ ei, const float* __restrict__ ew,
                            int* __restrict__ cursor, int2* __restrict__ col) {
  int e = blockIdx.x * blockDim.x + threadIdx.x;
  if (e >= N_EDGES) return;
  int d = ei[N_EDGES + e];
  int p = atomicAdd(&cursor[d], 1);
  unsigned long long v = ((unsigned long long)(unsigned)__float_as_int(ew[e]) << 32) |
                         (unsigned)ei[e];
  __builtin_nontemporal_store(v, (unsigned long long*)(col + p));
}

// ---------------- fp32 -> bf16 cast ----------------

__global__ void cast_bf16(const float* __restrict__ in, ushort* __restrict__ out, int n4) {
  int i = blockIdx.x * blockDim.x + threadIdx.x;
  if (i >= n4) return;
  float4 v = reinterpret_cast<const float4*>(in)[i];
  ushort4 o = make_ushort4(f2bf(v.x), f2bf(v.y), f2bf(v.z), f2bf(v.w));
  reinterpret_cast<ushort4*>(out)[i] = o;
}

// ---------------- gather-side segment sums (bf16 rows, 16B loads) ----------------

// 4 lanes per node, each owns 8 of 32 features (one uint4 = 8 bf16)
__global__ void gather_d32_bf(const ushort* __restrict__ xb, const int* __restrict__ rowptr,
                              const int2* __restrict__ col, float* __restrict__ agg) {
  int gid = blockIdx.x * blockDim.x + threadIdx.x;
  int n = gid >> 2;
  if (n >= N_NODES) return;
  int c = gid & 3;
  int beg = rowptr[n], end = rowptr[n + 1];
  float acc[8];
#pragma unroll
  for (int i = 0; i < 8; ++i) acc[i] = 0.f;
  for (int p = beg; p < end; ++p) {
    int src = col[p].x;
    uint4 u = *reinterpret_cast<const uint4*>(xb + (size_t)src * 32 + c * 8);
    unsigned uu[4] = {u.x, u.y, u.z, u.w};
#pragma unroll
    for (int i = 0; i < 4; ++i) {
      acc[2 * i]     += __uint_as_float(uu[i] << 16);
      acc[2 * i + 1] += __uint_as_float(uu[i] & 0xFFFF0000u);
    }
  }
  float* op = agg + (size_t)n * 32 + c * 8;
  *reinterpret_cast<float4*>(op)     = make_float4(acc[0], acc[1], acc[2], acc[3]);
  *reinterpret_cast<float4*>(op + 4) = make_float4(acc[4], acc[5], acc[6], acc[7]);
}

// 8 lanes per node, each owns 8 of 64 features.
// TRANS: apply per-feature relu(fma(v,sc,sh)) to each loaded element (BN1 on the fly)
template <bool WEIGHTED, bool TRANS>
__global__ void gather_d64_bf(const ushort* __restrict__ hb, const int* __restrict__ rowptr,
                              const int2* __restrict__ col,
                              const float* __restrict__ sc, const float* __restrict__ sh,
                              float* __restrict__ agg) {
  int gid = blockIdx.x * blockDim.x + threadIdx.x;
  int n = gid >> 3;
  if (n >= N_NODES) return;
  int c = gid & 7;
  int beg = rowptr[n], end = rowptr[n + 1];
  float sc8[8], sh8[8];
  if (TRANS) {
#pragma unroll
    for (int i = 0; i < 8; ++i) {
      sc8[i] = sc[c * 8 + i];
      sh8[i] = sh[c * 8 + i];
    }
  }
  float acc[8];
#pragma unroll
  for (int i = 0; i < 8; ++i) acc[i] = 0.f;
  for (int p = beg; p < end; ++p) {
    int2 ce = col[p];
    uint4 u = *reinterpret_cast<const uint4*>(hb + (size_t)ce.x * 64 + c * 8);
    float w = WEIGHTED ? __int_as_float(ce.y) : 1.f;
    unsigned uu[4] = {u.x, u.y, u.z, u.w};
#pragma unroll
    for (int i = 0; i < 4; ++i) {
      float lo = __uint_as_float(uu[i] << 16);
      float hi = __uint_as_float(uu[i] & 0xFFFF0000u);
      if (TRANS) {
        lo = fmaxf(fmaf(lo, sc8[2 * i], sh8[2 * i]), 0.f);
        hi = fmaxf(fmaf(hi, sc8[2 * i + 1], sh8[2 * i + 1]), 0.f);
      }
      if (WEIGHTED) {
        acc[2 * i]     = fmaf(lo, w, acc[2 * i]);
        acc[2 * i + 1] = fmaf(hi, w, acc[2 * i + 1]);
      } else {
        acc[2 * i]     += lo;
        acc[2 * i + 1] += hi;
      }
    }
  }
  float* op = agg + (size_t)n * 64 + c * 8;
  *reinterpret_cast<float4*>(op)     = make_float4(acc[0], acc[1], acc[2], acc[3]);
  *reinterpret_cast<float4*>(op + 4) = make_float4(acc[4], acc[5], acc[6], acc[7]);
}

// ---------------- LDS-tiled node GEMM with fused BN stats (atomic) ----------------
// out[M x DO] = [A1 | A2] @ [W1 ; W2]^T
// TA1: BN+relu A1 during staging (sc,sh indexed by k), write transformed back to h2act
// TA2: BN+relu A2 during staging (sc,sh indexed by k-K1), no write-back
// RADD: out += R before store/stats
// STATS: per-block {sum,sumsq} atomically added into sums[2*DO]
// OUTM: 0 = fp32, 1 = bf16, 2 = both (fp32 -> out, bf16 -> outb)

template <int K1, int K2, int DO, int TA1, int TA2, int RADD, int STATS, int OUTM>
__global__ __launch_bounds__(256) void gemm_node(
    const float* __restrict__ A1, const float* __restrict__ A2,
    const float* __restrict__ W1, const float* __restrict__ W2,
    const float* __restrict__ sc, const float* __restrict__ sh,
    const float* __restrict__ R, float* __restrict__ out, ushort* __restrict__ outb,
    float* h2act, float* __restrict__ sums) {
  constexpr int K = K1 + K2;
  constexpr int NC = K / 64;
  constexpr int NJB = DO / 64;
  __shared__ __align__(16) float A_lds[64][68];
  __shared__ __align__(16) float W_lds[64][DO + 4];

  const int tid = threadIdx.x;
  const int tx = tid & 15, ty = tid >> 4;
  const int nbase = blockIdx.x * 64;

  float4 acc[4][NJB];
#pragma unroll
  for (int i = 0; i < 4; ++i)
#pragma unroll
    for (int jb = 0; jb < NJB; ++jb) acc[i][jb] = make_float4(0.f, 0.f, 0.f, 0.f);

#pragma unroll 1
  for (int c = 0; c < NC; ++c) {
    const int kb = c * 64;
    if (c) __syncthreads();
#pragma unroll
    for (int it = 0; it < 4; ++it) {
      int idx = it * 256 + tid;
      int nl = idx >> 4;
      int kq = (idx & 15) * 4;
      int k = kb + kq;
      int ng = nbase + nl;
      float4 v = make_float4(0.f, 0.f, 0.f, 0.f);
      bool isA1 = (K2 == 0) || (k < K1);
      if (ng < N_NODES) {
        if (isA1)
          v = *reinterpret_cast<const float4*>(A1 + (size_t)ng * K1 + k);
        else
          v = *reinterpret_cast<const float4*>(A2 + (size_t)ng * K2 + (k - K1));
      }
      if constexpr (TA1) {
        if (isA1) {
          float4 s4 = *reinterpret_cast<const float4*>(sc + k);
          float4 h4 = *reinterpret_cast<const float4*>(sh + k);
          v.x = fmaxf(fmaf(v.x, s4.x, h4.x), 0.f);
          v.y = fmaxf(fmaf(v.y, s4.y, h4.y), 0.f);
          v.z = fmaxf(fmaf(v.z, s4.z, h4.z), 0.f);
          v.w = fmaxf(fmaf(v.w, s4.w, h4.w), 0.f);
          if (ng < N_NODES)
            *reinterpret_cast<float4*>(h2act + (size_t)ng * K1 + k) = v;
        }
      }
      if constexpr (TA2 && K2 > 0) {
        if (!isA1) {
          float4 s4 = *reinterpret_cast<const float4*>(sc + (k - K1));
          float4 h4 = *reinterpret_cast<const float4*>(sh + (k - K1));
          v.x = fmaxf(fmaf(v.x, s4.x, h4.x), 0.f);
          v.y = fmaxf(fmaf(v.y, s4.y, h4.y), 0.f);
          v.z = fmaxf(fmaf(v.z, s4.z, h4.z), 0.f);
          v.w = fmaxf(fmaf(v.w, s4.w, h4.w), 0.f);
        }
      }
      *reinterpret_cast<float4*>(&A_lds[nl][kq]) = v;
    }
#pragma unroll
    for (int it = 0; it < DO / 4; ++it) {
      int idx = it * 256 + tid;
      int j = idx >> 6;
      int kl = idx & 63;
      int k = kb + kl;
      float w;
      if (K2 == 0 || k < K1) w = W1[(size_t)j * K1 + k];
      else w = W2[(size_t)j * K2 + (k - K1)];
      W_lds[kl][j] = w;
    }
    __syncthreads();
#pragma unroll 4
    for (int k4 = 0; k4 < 16; ++k4) {
      float4 a[4];
#pragma unroll
      for (int i = 0; i < 4; ++i)
        a[i] = *reinterpret_cast<const float4*>(&A_lds[ty * 4 + i][k4 * 4]);
#pragma unroll
      for (int q = 0; q < 4; ++q) {
#pragma unroll
        for (int jb = 0; jb < NJB; ++jb) {
          float4 w = *reinterpret_cast<const float4*>(&W_lds[k4 * 4 + q][jb * 64 + tx * 4]);
#pragma unroll
          for (int i = 0; i < 4; ++i) {
            float av = reinterpret_cast<const float*>(&a[i])[q];
            acc[i][jb].x = fmaf(av, w.x, acc[i][jb].x);
            acc[i][jb].y = fmaf(av, w.y, acc[i][jb].y);
            acc[i][jb].z = fmaf(av, w.z, acc[i][jb].z);
            acc[i][jb].w = fmaf(av, w.w, acc[i][jb].w);
          }
        }
      }
    }
  }
  // ---- R add (into acc so stats see it) + output ----
#pragma unroll
  for (int i = 0; i < 4; ++i) {
    int ng = nbase + ty * 4 + i;
    if (ng >= N_NODES) continue;
#pragma unroll
    for (int jb = 0; jb < NJB; ++jb) {
      if constexpr (RADD) {
        float4 rr = *reinterpret_cast<const float4*>(R + (size_t)ng * DO + jb * 64 + tx * 4);
        acc[i][jb].x += rr.x; acc[i][jb].y += rr.y;
        acc[i][jb].z += rr.z; acc[i][jb].w += rr.w;
      }
      size_t off = (size_t)ng * DO + jb * 64 + tx * 4;
      if constexpr (OUTM == 1) {
        ushort4 o = make_ushort4(f2bf(acc[i][jb].x), f2bf(acc[i][jb].y),
                                 f2bf(acc[i][jb].z), f2bf(acc[i][jb].w));
        *reinterpret_cast<ushort4*>((ushort*)out + off) = o;
      } else {
        *reinterpret_cast<float4*>(out + off) = acc[i][jb];
        if constexpr (OUTM == 2) {
          ushort4 o = make_ushort4(f2bf(acc[i][jb].x), f2bf(acc[i][jb].y),
                                   f2bf(acc[i][jb].z), f2bf(acc[i][jb].w));
          *reinterpret_cast<ushort4*>(outb + off) = o;
        }
      }
    }
  }
  // ---- fused BN stats: block-local LDS reduce, then one atomic per column ----
  if constexpr (STATS) {
    __syncthreads();  // done reading A_lds/W_lds; safe to reuse
    float* sums_l = &A_lds[0][0];  // [16][DO]
    float* sq_l = &W_lds[0][0];    // [16][DO]
#pragma unroll
    for (int jb = 0; jb < NJB; ++jb) {
      float4 s = make_float4(0.f, 0.f, 0.f, 0.f);
      float4 q = make_float4(0.f, 0.f, 0.f, 0.f);
#pragma unroll
      for (int i = 0; i < 4; ++i) {
        if (nbase + ty * 4 + i < N_NODES) {
          float4 v = acc[i][jb];
          s.x += v.x; s.y += v.y; s.z += v.z; s.w += v.w;
          q.x = fmaf(v.x, v.x, q.x); q.y = fmaf(v.y, v.y, q.y);
          q.z = fmaf(v.z, v.z, q.z); q.w = fmaf(v.w, v.w, q.w);
        }
      }
      *reinterpret_cast<float4*>(&sums_l[ty * DO + jb * 64 + tx * 4]) = s;
      *reinterpret_cast<float4*>(&sq_l[ty * DO + jb * 64 + tx * 4]) = q;
    }
    __syncthreads();
    if (tid < DO) {
      float s = 0.f, q = 0.f;
#pragma unroll
      for (int t = 0; t < 16; ++t) {
        s += sums_l[t * DO + tid];
        q += sq_l[t * DO + tid];
      }
      unsafeAtomicAdd(&sums[tid], s);
      unsafeAtomicAdd(&sums[DO + tid], q);
    }
  }
}

// ---------------- BN finalize ----------------

__global__ void bn_finalize(const float* __restrict__ sums, const float* __restrict__ g,
                            const float* __restrict__ be, float* __restrict__ sc,
                            float* __restrict__ sh, int D) {
  int j = threadIdx.x;
  if (j >= D) return;
  const float invN = 1.f / (float)N_NODES;
  float mean = sums[j] * invN;
  float var = sums[D + j] * invN - mean * mean;
  float r = rsqrtf(var + EPSV);
  float scale = g[j] * r;
  sc[j] = scale;
  sh[j] = be[j] - mean * scale;
}

// ---------------- fused residual + classifier ----------------
// h1 = relu(bn1(h1pre)); t = relu(bn3(h3p) + h1); c = relu(t@Wc1^T+bc1); out = c@Wc2^T+bc2

__global__ __launch_bounds__(256) void final_fused(
    const float* __restrict__ h3p, const float* __restrict__ h1p,
    const float* __restrict__ sc1, const float* __restrict__ sh1,
    const float* __restrict__ sc3, const float* __restrict__ sh3,
    const float* __restrict__ Wc1, const float* __restrict__ bc1,
    const float* __restrict__ Wc2, const float* __restrict__ bc2,
    float* __restrict__ out) {
  __shared__ __align__(16) float t_lds[64][68];
  __shared__ __align__(16) float w1_lds[64][36];
  __shared__ __align__(16) float c_lds[64][36];
  __shared__ __align__(16) float w2_lds[64];
  __shared__ __align__(16) float b1_lds[32];
  __shared__ float b2_lds[2];
  const int tid = threadIdx.x;
  const int nbase = blockIdx.x * 64;

#pragma unroll
  for (int it = 0; it < 4; ++it) {
    int idx = it * 256 + tid;
    int nl = idx >> 4;
    int k = (idx & 15) * 4;
    int ng = nbase + nl;
    float4 v = make_float4(0.f, 0.f, 0.f, 0.f);
    if (ng < N_NODES) {
      float4 p = *reinterpret_cast<const float4*>(h3p + (size_t)ng * 64 + k);
      float4 u = *reinterpret_cast<const float4*>(h1p + (size_t)ng * 64 + k);
      float4 sa = *reinterpret_cast<const float4*>(sc1 + k);
      float4 ha = *reinterpret_cast<const float4*>(sh1 + k);
      float4 sb = *reinterpret_cast<const float4*>(sc3 + k);
      float4 hb = *reinterpret_cast<const float4*>(sh3 + k);
      float h1x = fmaxf(fmaf(u.x, sa.x, ha.x), 0.f);
      float h1y = fmaxf(fmaf(u.y, sa.y, ha.y), 0.f);
      float h1z = fmaxf(fmaf(u.z, sa.z, ha.z), 0.f);
      float h1w = fmaxf(fmaf(u.w, sa.w, ha.w), 0.f);
      v.x = fmaxf(fmaf(p.x, sb.x, hb.x) + h1x, 0.f);
      v.y = fmaxf(fmaf(p.y, sb.y, hb.y) + h1y, 0.f);
      v.z = fmaxf(fmaf(p.z, sb.z, hb.z) + h1z, 0.f);
      v.w = fmaxf(fmaf(p.w, sb.w, hb.w) + h1w, 0.f);
    }
    *reinterpret_cast<float4*>(&t_lds[nl][k]) = v;
  }
#pragma unroll
  for (int it = 0; it < 8; ++it) {
    int idx = it * 256 + tid;
    int j = idx >> 6;
    int k = idx & 63;
    w1_lds[k][j] = Wc1[(size_t)j * 64 + k];
  }
  if (tid < 64) w2_lds[tid] = Wc2[tid];
  else if (tid < 96) b1_lds[tid - 64] = bc1[tid - 64];
  else if (tid < 98) b2_lds[tid - 96] = bc2[tid - 96];
  __syncthreads();

  {
    const int tx = tid & 7, ty = tid >> 3;
    float4 a0c = make_float4(0.f, 0.f, 0.f, 0.f);
    float4 a1c = make_float4(0.f, 0.f, 0.f, 0.f);
#pragma unroll 4
    for (int k4 = 0; k4 < 16; ++k4) {
      float4 a0 = *reinterpret_cast<const float4*>(&t_lds[ty * 2 + 0][k4 * 4]);
      float4 a1 = *reinterpret_cast<const float4*>(&t_lds[ty * 2 + 1][k4 * 4]);
#pragma unroll
      for (int q = 0; q < 4; ++q) {
        float4 w = *reinterpret_cast<const float4*>(&w1_lds[k4 * 4 + q][tx * 4]);
        float a0q = reinterpret_cast<const float*>(&a0)[q];
        float a1q = reinterpret_cast<const float*>(&a1)[q];
        a0c.x = fmaf(a0q, w.x, a0c.x); a0c.y = fmaf(a0q, w.y, a0c.y);
        a0c.z = fmaf(a0q, w.z, a0c.z); a0c.w = fmaf(a0q, w.w, a0c.w);
        a1c.x = fmaf(a1q, w.x, a1c.x); a1c.y = fmaf(a1q, w.y, a1c.y);
        a1c.z = fmaf(a1q, w.z, a1c.z); a1c.w = fmaf(a1q, w.w, a1c.w);
      }
    }
    float4 b = *reinterpret_cast<const float4*>(&b1_lds[tx * 4]);
    a0c.x = fmaxf(a0c.x + b.x, 0.f); a0c.y = fmaxf(a0c.y + b.y, 0.f);
    a0c.z = fmaxf(a0c.z + b.z, 0.f); a0c.w = fmaxf(a0c.w + b.w, 0.f);
    a1c.x = fmaxf(a1c.x + b.x, 0.f); a1c.y = fmaxf(a1c.y + b.y, 0.f);
    a1c.z = fmaxf(a1c.z + b.z, 0.f); a1c.w = fmaxf(a1c.w + b.w, 0.f);
    *reinterpret_cast<float4*>(&c_lds[ty * 2 + 0][tx * 4]) = a0c;
    *reinterpret_cast<float4*>(&c_lds[ty * 2 + 1][tx * 4]) = a1c;
  }
  __syncthreads();

  if (tid < 128) {
    int nl = tid >> 1, o = tid & 1;
    int ng = nbase + nl;
    if (ng < N_NODES) {
      float s = b2_lds[o];
#pragma unroll
      for (int k = 0; k < 32; ++k) s = fmaf(c_lds[nl][k], w2_lds[o * 32 + k], s);
      out[(size_t)ng * 2 + o] = s;
    }
  }
}

// ---------------- launcher ----------------

extern "C" void kernel_launch(void* const* d_in, const int* in_sizes, int n_in,
                              void* d_out, int out_size, void* d_ws, size_t ws_size,
                              hipStream_t stream) {
  const float* x      = (const float*)d_in[0];
  const int*   ei     = (const int*)d_in[1];
  const float* ew     = (const float*)d_in[2];
  const float* W1rel  = (const float*)d_in[3];
  const float* W1root = (const float*)d_in[5];
  const float* W2rel  = (const float*)d_in[6];
  const float* W2root = (const float*)d_in[8];
  const float* W3rel  = (const float*)d_in[9];
  const float* W3root = (const float*)d_in[11];
  const float* g1  = (const float*)d_in[12];
  const float* be1 = (const float*)d_in[13];
  const float* g2  = (const float*)d_in[14];
  const float* be2 = (const float*)d_in[15];
  const float* g3  = (const float*)d_in[16];
  const float* be3 = (const float*)d_in[17];
  const float* Wc1 = (const float*)d_in[18];
  const float* bc1 = (const float*)d_in[19];
  const float* Wc2 = (const float*)d_in[20];
  const float* bc2 = (const float*)d_in[21];

  float* ws = (float*)d_ws;
  const size_t NF = (size_t)N_NODES * 64;
  float* A = ws;            // agg1 (N*32) -> agg2 (N*64) -> agg3 (N*64)
  float* B = ws + NF;       // xb(bf16) -> y2b(bf16) -> h3pre(fp32)
  float* C = ws + 2 * NF;   // h1pre fp32, live to the end
  float* E = ws + 3 * NF;   // h1preb(bf16) -> h2pre/h2act fp32 (N*128)
  float* X = ws + 5 * NF;
  float* S = X;                                // 1024 floats: sums + sc/sh slots
  int* rowptr   = (int*)(X + 1024);            // N+2
  int* cnt      = rowptr + (N_NODES + 2);      // N
  int* cursor   = cnt + N_NODES;               // N
  int* blocksum = cursor + N_NODES;            // 128
  int2* col     = (int2*)(blocksum + 128);     // E packed (src, w)
  // S: sums1@0(128) sc1@128 sh1@192 | sums2@256(256) sc2@512 sh2@640 |
  //    sums3@768(128) sc3@896 sh3@960

  ushort* xb     = (ushort*)B;  // N*32 bf16, dead after gather1
  ushort* h1preb = (ushort*)E;  // N*64 bf16, dead after gather2
  ushort* y2b    = (ushort*)B;  // N*64 bf16, dead after gather3

  hipMemsetAsync(S, 0, 1024 * sizeof(float), stream);
  hipMemsetAsync(cnt, 0, N_NODES * sizeof(int), stream);

  const int edgeBlocks = (N_EDGES + 255) / 256;
  const int tileBlocks = (N_NODES + 63) / 64;  // 1563

  // x -> bf16 (independent of CSR build)
  cast_bf16<<<(N_NODES * 32 / 4 + 255) / 256, 256, 0, stream>>>(x, xb, N_NODES * 32 / 4);

  // CSR build (by destination)
  hist_kernel<<<edgeBlocks, 256, 0, stream>>>(ei, cnt);
  scan_phase1<<<SCAN_NB, 256, 0, stream>>>(cnt, blocksum);
  scan_phase2<<<1, 128, 0, stream>>>(blocksum, rowptr);
  scan_phase3<<<SCAN_NB, 256, 0, stream>>>(cnt, blocksum, rowptr, cursor);
  fill_kernel<<<edgeBlocks, 256, 0, stream>>>(ei, ew, cursor, col);

  // ---- layer 1 ----
  gather_d32_bf<<<(N_NODES * 4 + 255) / 256, 256, 0, stream>>>(xb, rowptr, col, A);
  gemm_node<32, 32, 64, 0, 0, 0, 1, 2><<<tileBlocks, 256, 0, stream>>>(
      A, x, W1rel, W1root, nullptr, nullptr, nullptr, C, h1preb, nullptr, S);
  bn_finalize<<<1, 128, 0, stream>>>(S, g1, be1, S + 128, S + 192, 64);

  // ---- layer 2 (BN1+relu fused into gather and gemm2 staging) ----
  gather_d64_bf<false, true><<<(N_NODES * 8 + 255) / 256, 256, 0, stream>>>(
      h1preb, rowptr, col, S + 128, S + 192, A);
  gemm_node<64, 64, 128, 0, 1, 0, 1, 0><<<tileBlocks, 256, 0, stream>>>(
      A, C, W2rel, W2root, S + 128, S + 192, nullptr, E, nullptr, nullptr, S + 256);
  bn_finalize<<<1, 128, 0, stream>>>(S + 256, g2, be2, S + 512, S + 640, 128);

  // y2b = bf16( relu(bn2(h2pre)) @ W3rel^T ); h2act -> E in place
  gemm_node<128, 0, 64, 1, 0, 0, 0, 1><<<tileBlocks, 256, 0, stream>>>(
      E, nullptr, W3rel, nullptr, S + 512, S + 640, nullptr, (float*)y2b, nullptr, E, nullptr);

  // ---- layer 3 ----
  gather_d64_bf<true, false><<<(N_NODES * 8 + 255) / 256, 256, 0, stream>>>(
      y2b, rowptr, col, nullptr, nullptr, A);
  gemm_node<128, 0, 64, 0, 0, 1, 1, 0><<<tileBlocks, 256, 0, stream>>>(
      E, nullptr, W3root, nullptr, nullptr, nullptr, A, B, nullptr, nullptr, S + 768);
  bn_finalize<<<1, 128, 0, stream>>>(S + 768, g3, be3, S + 896, S + 960, 64);

  // ---- residual + classifier ----
  final_fused<<<tileBlocks, 256, 0, stream>>>(B, C, S + 128, S + 192, S + 896, S + 960,
                                              Wc1, bc1, Wc2, bc2, (float*)d_out);
}

// Round 9
// 569.815 us; speedup vs baseline: 1.7268x; 1.0741x over previous
//
#include <hip/hip_runtime.h>

#define N_NODES 100000
#define N_EDGES 1600000
#define EPSV 1e-5f

__device__ __forceinline__ ushort f2bf(float f) {
  unsigned u = __float_as_uint(f);
  unsigned r = (u + 0x7FFFu + ((u >> 16) & 1u)) >> 16;
  return (ushort)r;
}

// ---------------- CSR-by-destination build ----------------

__global__ void hist_kernel(const int* __restrict__ ei, int* __restrict__ cnt) {
  int e = blockIdx.x * blockDim.x + threadIdx.x;
  if (e >= N_EDGES) return;
  atomicAdd(&cnt[ei[N_EDGES + e]], 1);
}

#define SCAN_BLK 1024
#define SCAN_NB ((N_NODES + SCAN_BLK - 1) / SCAN_BLK)  // 98

__global__ void scan_phase1(const int* __restrict__ cnt, int* __restrict__ blocksum) {
  __shared__ int part[256];
  int base = blockIdx.x * SCAN_BLK + threadIdx.x * 4;
  int s = 0;
#pragma unroll
  for (int i = 0; i < 4; ++i) {
    int idx = base + i;
    if (idx < N_NODES) s += cnt[idx];
  }
  part[threadIdx.x] = s;
  __syncthreads();
  for (int d = 128; d > 0; d >>= 1) {
    if (threadIdx.x < d) part[threadIdx.x] += part[threadIdx.x + d];
    __syncthreads();
  }
  if (threadIdx.x == 0) blocksum[blockIdx.x] = part[0];
}

__global__ void scan_phase2(int* __restrict__ blocksum, int* __restrict__ rowptr) {
  __shared__ int part[128];
  int tid = threadIdx.x;
  int v = (tid < SCAN_NB) ? blocksum[tid] : 0;
  part[tid] = v;
  __syncthreads();
  for (int d = 1; d < 128; d <<= 1) {
    int t = (tid >= d) ? part[tid - d] : 0;
    __syncthreads();
    part[tid] += t;
    __syncthreads();
  }
  if (tid < SCAN_NB) blocksum[tid] = part[tid] - v;  // exclusive
  if (tid == 127) rowptr[N_NODES] = part[127];
}

__global__ void scan_phase3(const int* __restrict__ cnt, const int* __restrict__ blocksum,
                            int* __restrict__ rowptr, int* __restrict__ cursor) {
  __shared__ int part[256];
  int base = blockIdx.x * SCAN_BLK + threadIdx.x * 4;
  int c[4];
  int s = 0;
#pragma unroll
  for (int i = 0; i < 4; ++i) {
    int idx = base + i;
    c[i] = (idx < N_NODES) ? cnt[idx] : 0;
    s += c[i];
  }
  part[threadIdx.x] = s;
  __syncthreads();
  int me = s;
  for (int d = 1; d < 256; d <<= 1) {
    int t = (threadIdx.x >= d) ? part[threadIdx.x - d] : 0;
    __syncthreads();
    part[threadIdx.x] += t;
    __syncthreads();
  }
  int off = blocksum[blockIdx.x] + part[threadIdx.x] - me;
#pragma unroll
  for (int i = 0; i < 4; ++i) {
    int idx = base + i;
    if (idx < N_NODES) {
      rowptr[idx] = off;
      cursor[idx] = off;
      off += c[i];
    }
  }
}

// packed fill: one 4B store per edge: (bf16(w) without sign) << 17 | src
__global__ void fill_kernel(const int* __restrict__ ei, const float* __restrict__ ew,
                            int* __restrict__ cursor, unsigned* __restrict__ col) {
  int e = blockIdx.x * blockDim.x + threadIdx.x;
  if (e >= N_EDGES) return;
  int d = ei[N_EDGES + e];
  int p = atomicAdd(&cursor[d], 1);
  col[p] = ((unsigned)f2bf(ew[e]) << 17) | (unsigned)ei[e];
}

// ---------------- fp32 -> bf16 cast ----------------

__global__ void cast_bf16(const float* __restrict__ in, ushort* __restrict__ out, int n4) {
  int i = blockIdx.x * blockDim.x + threadIdx.x;
  if (i >= n4) return;
  float4 v = reinterpret_cast<const float4*>(in)[i];
  ushort4 o = make_ushort4(f2bf(v.x), f2bf(v.y), f2bf(v.z), f2bf(v.w));
  reinterpret_cast<ushort4*>(out)[i] = o;
}

// ---------------- gather-side segment sums (bf16 rows, 16B loads, 2x unroll) ----------------

#define SRC_OF(v) ((v) & 0x1FFFFu)
#define W_OF(v) __uint_as_float(((v) >> 17) << 16)

// 4 lanes per node, each owns 8 of 32 features (one uint4 = 8 bf16)
__global__ void gather_d32_bf(const ushort* __restrict__ xb, const int* __restrict__ rowptr,
                              const unsigned* __restrict__ col, float* __restrict__ agg) {
  int gid = blockIdx.x * blockDim.x + threadIdx.x;
  int n = gid >> 2;
  if (n >= N_NODES) return;
  int c = gid & 3;
  int beg = rowptr[n], end = rowptr[n + 1];
  float acc[8];
#pragma unroll
  for (int i = 0; i < 8; ++i) acc[i] = 0.f;
  int p = beg;
  for (; p + 1 < end; p += 2) {
    unsigned e0 = col[p], e1 = col[p + 1];
    uint4 u0 = *reinterpret_cast<const uint4*>(xb + (size_t)SRC_OF(e0) * 32 + c * 8);
    uint4 u1 = *reinterpret_cast<const uint4*>(xb + (size_t)SRC_OF(e1) * 32 + c * 8);
    unsigned a0[4] = {u0.x, u0.y, u0.z, u0.w};
    unsigned a1[4] = {u1.x, u1.y, u1.z, u1.w};
#pragma unroll
    for (int i = 0; i < 4; ++i) {
      acc[2 * i]     += __uint_as_float(a0[i] << 16) + __uint_as_float(a1[i] << 16);
      acc[2 * i + 1] += __uint_as_float(a0[i] & 0xFFFF0000u) +
                        __uint_as_float(a1[i] & 0xFFFF0000u);
    }
  }
  if (p < end) {
    unsigned e0 = col[p];
    uint4 u0 = *reinterpret_cast<const uint4*>(xb + (size_t)SRC_OF(e0) * 32 + c * 8);
    unsigned a0[4] = {u0.x, u0.y, u0.z, u0.w};
#pragma unroll
    for (int i = 0; i < 4; ++i) {
      acc[2 * i]     += __uint_as_float(a0[i] << 16);
      acc[2 * i + 1] += __uint_as_float(a0[i] & 0xFFFF0000u);
    }
  }
  float* op = agg + (size_t)n * 32 + c * 8;
  *reinterpret_cast<float4*>(op)     = make_float4(acc[0], acc[1], acc[2], acc[3]);
  *reinterpret_cast<float4*>(op + 4) = make_float4(acc[4], acc[5], acc[6], acc[7]);
}

// 8 lanes per node, each owns 8 of 64 features.
// TRANS: apply per-feature relu(fma(v,sc,sh)) to each loaded element (BN1 on the fly)
template <bool WEIGHTED, bool TRANS>
__global__ void gather_d64_bf(const ushort* __restrict__ hb, const int* __restrict__ rowptr,
                              const unsigned* __restrict__ col,
                              const float* __restrict__ sc, const float* __restrict__ sh,
                              float* __restrict__ agg) {
  int gid = blockIdx.x * blockDim.x + threadIdx.x;
  int n = gid >> 3;
  if (n >= N_NODES) return;
  int c = gid & 7;
  int beg = rowptr[n], end = rowptr[n + 1];
  float sc8[8], sh8[8];
  if (TRANS) {
#pragma unroll
    for (int i = 0; i < 8; ++i) {
      sc8[i] = sc[c * 8 + i];
      sh8[i] = sh[c * 8 + i];
    }
  }
  float acc[8];
#pragma unroll
  for (int i = 0; i < 8; ++i) acc[i] = 0.f;

  auto body = [&](unsigned ev, const uint4& u) {
    float w = WEIGHTED ? W_OF(ev) : 1.f;
    unsigned uu[4] = {u.x, u.y, u.z, u.w};
#pragma unroll
    for (int i = 0; i < 4; ++i) {
      float lo = __uint_as_float(uu[i] << 16);
      float hi = __uint_as_float(uu[i] & 0xFFFF0000u);
      if (TRANS) {
        lo = fmaxf(fmaf(lo, sc8[2 * i], sh8[2 * i]), 0.f);
        hi = fmaxf(fmaf(hi, sc8[2 * i + 1], sh8[2 * i + 1]), 0.f);
      }
      if (WEIGHTED) {
        acc[2 * i]     = fmaf(lo, w, acc[2 * i]);
        acc[2 * i + 1] = fmaf(hi, w, acc[2 * i + 1]);
      } else {
        acc[2 * i]     += lo;
        acc[2 * i + 1] += hi;
      }
    }
  };

  int p = beg;
  for (; p + 1 < end; p += 2) {
    unsigned e0 = col[p], e1 = col[p + 1];
    uint4 u0 = *reinterpret_cast<const uint4*>(hb + (size_t)SRC_OF(e0) * 64 + c * 8);
    uint4 u1 = *reinterpret_cast<const uint4*>(hb + (size_t)SRC_OF(e1) * 64 + c * 8);
    body(e0, u0);
    body(e1, u1);
  }
  if (p < end) {
    unsigned e0 = col[p];
    uint4 u0 = *reinterpret_cast<const uint4*>(hb + (size_t)SRC_OF(e0) * 64 + c * 8);
    body(e0, u0);
  }
  float* op = agg + (size_t)n * 64 + c * 8;
  *reinterpret_cast<float4*>(op)     = make_float4(acc[0], acc[1], acc[2], acc[3]);
  *reinterpret_cast<float4*>(op + 4) = make_float4(acc[4], acc[5], acc[6], acc[7]);
}

// ---------------- LDS-tiled node GEMM with fused BN stats (atomic) ----------------
// out[M x DO] = [A1 | A2] @ [W1 ; W2]^T
// TA1: BN+relu A1 during staging (sc,sh indexed by k), write transformed back to h2act
// TA2: BN+relu A2 during staging (sc,sh indexed by k-K1), no write-back
// RADD: out += R before store/stats
// STATS: per-block {sum,sumsq} atomically added into sums[2*DO]
// OUTM: 0 = fp32, 1 = bf16, 2 = both (fp32 -> out, bf16 -> outb)

template <int K1, int K2, int DO, int TA1, int TA2, int RADD, int STATS, int OUTM>
__global__ __launch_bounds__(256) void gemm_node(
    const float* __restrict__ A1, const float* __restrict__ A2,
    const float* __restrict__ W1, const float* __restrict__ W2,
    const float* __restrict__ sc, const float* __restrict__ sh,
    const float* __restrict__ R, float* __restrict__ out, ushort* __restrict__ outb,
    float* h2act, float* __restrict__ sums) {
  constexpr int K = K1 + K2;
  constexpr int NC = K / 64;
  constexpr int NJB = DO / 64;
  __shared__ __align__(16) float A_lds[64][68];
  __shared__ __align__(16) float W_lds[64][DO + 4];

  const int tid = threadIdx.x;
  const int tx = tid & 15, ty = tid >> 4;
  const int nbase = blockIdx.x * 64;

  float4 acc[4][NJB];
#pragma unroll
  for (int i = 0; i < 4; ++i)
#pragma unroll
    for (int jb = 0; jb < NJB; ++jb) acc[i][jb] = make_float4(0.f, 0.f, 0.f, 0.f);

#pragma unroll 1
  for (int c = 0; c < NC; ++c) {
    const int kb = c * 64;
    if (c) __syncthreads();
#pragma unroll
    for (int it = 0; it < 4; ++it) {
      int idx = it * 256 + tid;
      int nl = idx >> 4;
      int kq = (idx & 15) * 4;
      int k = kb + kq;
      int ng = nbase + nl;
      float4 v = make_float4(0.f, 0.f, 0.f, 0.f);
      bool isA1 = (K2 == 0) || (k < K1);
      if (ng < N_NODES) {
        if (isA1)
          v = *reinterpret_cast<const float4*>(A1 + (size_t)ng * K1 + k);
        else
          v = *reinterpret_cast<const float4*>(A2 + (size_t)ng * K2 + (k - K1));
      }
      if constexpr (TA1) {
        if (isA1) {
          float4 s4 = *reinterpret_cast<const float4*>(sc + k);
          float4 h4 = *reinterpret_cast<const float4*>(sh + k);
          v.x = fmaxf(fmaf(v.x, s4.x, h4.x), 0.f);
          v.y = fmaxf(fmaf(v.y, s4.y, h4.y), 0.f);
          v.z = fmaxf(fmaf(v.z, s4.z, h4.z), 0.f);
          v.w = fmaxf(fmaf(v.w, s4.w, h4.w), 0.f);
          if (ng < N_NODES)
            *reinterpret_cast<float4*>(h2act + (size_t)ng * K1 + k) = v;
        }
      }
      if constexpr (TA2 && K2 > 0) {
        if (!isA1) {
          float4 s4 = *reinterpret_cast<const float4*>(sc + (k - K1));
          float4 h4 = *reinterpret_cast<const float4*>(sh + (k - K1));
          v.x = fmaxf(fmaf(v.x, s4.x, h4.x), 0.f);
          v.y = fmaxf(fmaf(v.y, s4.y, h4.y), 0.f);
          v.z = fmaxf(fmaf(v.z, s4.z, h4.z), 0.f);
          v.w = fmaxf(fmaf(v.w, s4.w, h4.w), 0.f);
        }
      }
      *reinterpret_cast<float4*>(&A_lds[nl][kq]) = v;
    }
#pragma unroll
    for (int it = 0; it < DO / 4; ++it) {
      int idx = it * 256 + tid;
      int j = idx >> 6;
      int kl = idx & 63;
      int k = kb + kl;
      float w;
      if (K2 == 0 || k < K1) w = W1[(size_t)j * K1 + k];
      else w = W2[(size_t)j * K2 + (k - K1)];
      W_lds[kl][j] = w;
    }
    __syncthreads();
#pragma unroll 4
    for (int k4 = 0; k4 < 16; ++k4) {
      float4 a[4];
#pragma unroll
      for (int i = 0; i < 4; ++i)
        a[i] = *reinterpret_cast<const float4*>(&A_lds[ty * 4 + i][k4 * 4]);
#pragma unroll
      for (int q = 0; q < 4; ++q) {
#pragma unroll
        for (int jb = 0; jb < NJB; ++jb) {
          float4 w = *reinterpret_cast<const float4*>(&W_lds[k4 * 4 + q][jb * 64 + tx * 4]);
#pragma unroll
          for (int i = 0; i < 4; ++i) {
            float av = reinterpret_cast<const float*>(&a[i])[q];
            acc[i][jb].x = fmaf(av, w.x, acc[i][jb].x);
            acc[i][jb].y = fmaf(av, w.y, acc[i][jb].y);
            acc[i][jb].z = fmaf(av, w.z, acc[i][jb].z);
            acc[i][jb].w = fmaf(av, w.w, acc[i][jb].w);
          }
        }
      }
    }
  }
  // ---- R add (into acc so stats see it) + output ----
#pragma unroll
  for (int i = 0; i < 4; ++i) {
    int ng = nbase + ty * 4 + i;
    if (ng >= N_NODES) continue;
#pragma unroll
    for (int jb = 0; jb < NJB; ++jb) {
      if constexpr (RADD) {
        float4 rr = *reinterpret_cast<const float4*>(R + (size_t)ng * DO + jb * 64 + tx * 4);
        acc[i][jb].x += rr.x; acc[i][jb].y += rr.y;
        acc[i][jb].z += rr.z; acc[i][jb].w += rr.w;
      }
      size_t off = (size_t)ng * DO + jb * 64 + tx * 4;
      if constexpr (OUTM == 1) {
        ushort4 o = make_ushort4(f2bf(acc[i][jb].x), f2bf(acc[i][jb].y),
                                 f2bf(acc[i][jb].z), f2bf(acc[i][jb].w));
        *reinterpret_cast<ushort4*>((ushort*)out + off) = o;
      } else {
        *reinterpret_cast<float4*>(out + off) = acc[i][jb];
        if constexpr (OUTM == 2) {
          ushort4 o = make_ushort4(f2bf(acc[i][jb].x), f2bf(acc[i][jb].y),
                                   f2bf(acc[i][jb].z), f2bf(acc[i][jb].w));
          *reinterpret_cast<ushort4*>(outb + off) = o;
        }
      }
    }
  }
  // ---- fused BN stats: block-local LDS reduce, then one atomic per column ----
  if constexpr (STATS) {
    __syncthreads();  // done reading A_lds/W_lds; safe to reuse
    float* sums_l = &A_lds[0][0];  // [16][DO]
    float* sq_l = &W_lds[0][0];    // [16][DO]
#pragma unroll
    for (int jb = 0; jb < NJB; ++jb) {
      float4 s = make_float4(0.f, 0.f, 0.f, 0.f);
      float4 q = make_float4(0.f, 0.f, 0.f, 0.f);
#pragma unroll
      for (int i = 0; i < 4; ++i) {
        if (nbase + ty * 4 + i < N_NODES) {
          float4 v = acc[i][jb];
          s.x += v.x; s.y += v.y; s.z += v.z; s.w += v.w;
          q.x = fmaf(v.x, v.x, q.x); q.y = fmaf(v.y, v.y, q.y);
          q.z = fmaf(v.z, v.z, q.z); q.w = fmaf(v.w, v.w, q.w);
        }
      }
      *reinterpret_cast<float4*>(&sums_l[ty * DO + jb * 64 + tx * 4]) = s;
      *reinterpret_cast<float4*>(&sq_l[ty * DO + jb * 64 + tx * 4]) = q;
    }
    __syncthreads();
    if (tid < DO) {
      float s = 0.f, q = 0.f;
#pragma unroll
      for (int t = 0; t < 16; ++t) {
        s += sums_l[t * DO + tid];
        q += sq_l[t * DO + tid];
      }
      unsafeAtomicAdd(&sums[tid], s);
      unsafeAtomicAdd(&sums[DO + tid], q);
    }
  }
}

// ---------------- BN finalize ----------------

__global__ void bn_finalize(const float* __restrict__ sums, const float* __restrict__ g,
                            const float* __restrict__ be, float* __restrict__ sc,
                            float* __restrict__ sh, int D) {
  int j = threadIdx.x;
  if (j >= D) return;
  const float invN = 1.f / (float)N_NODES;
  float mean = sums[j] * invN;
  float var = sums[D + j] * invN - mean * mean;
  float r = rsqrtf(var + EPSV);
  float scale = g[j] * r;
  sc[j] = scale;
  sh[j] = be[j] - mean * scale;
}

// ---------------- fused residual + classifier ----------------
// h1 = relu(bn1(h1pre)); t = relu(bn3(h3p) + h1); c = relu(t@Wc1^T+bc1); out = c@Wc2^T+bc2

__global__ __launch_bounds__(256) void final_fused(
    const float* __restrict__ h3p, const float* __restrict__ h1p,
    const float* __restrict__ sc1, const float* __restrict__ sh1,
    const float* __restrict__ sc3, const float* __restrict__ sh3,
    const float* __restrict__ Wc1, const float* __restrict__ bc1,
    const float* __restrict__ Wc2, const float* __restrict__ bc2,
    float* __restrict__ out) {
  __shared__ __align__(16) float t_lds[64][68];
  __shared__ __align__(16) float w1_lds[64][36];
  __shared__ __align__(16) float c_lds[64][36];
  __shared__ __align__(16) float w2_lds[64];
  __shared__ __align__(16) float b1_lds[32];
  __shared__ float b2_lds[2];
  const int tid = threadIdx.x;
  const int nbase = blockIdx.x * 64;

#pragma unroll
  for (int it = 0; it < 4; ++it) {
    int idx = it * 256 + tid;
    int nl = idx >> 4;
    int k = (idx & 15) * 4;
    int ng = nbase + nl;
    float4 v = make_float4(0.f, 0.f, 0.f, 0.f);
    if (ng < N_NODES) {
      float4 p = *reinterpret_cast<const float4*>(h3p + (size_t)ng * 64 + k);
      float4 u = *reinterpret_cast<const float4*>(h1p + (size_t)ng * 64 + k);
      float4 sa = *reinterpret_cast<const float4*>(sc1 + k);
      float4 ha = *reinterpret_cast<const float4*>(sh1 + k);
      float4 sb = *reinterpret_cast<const float4*>(sc3 + k);
      float4 hb = *reinterpret_cast<const float4*>(sh3 + k);
      float h1x = fmaxf(fmaf(u.x, sa.x, ha.x), 0.f);
      float h1y = fmaxf(fmaf(u.y, sa.y, ha.y), 0.f);
      float h1z = fmaxf(fmaf(u.z, sa.z, ha.z), 0.f);
      float h1w = fmaxf(fmaf(u.w, sa.w, ha.w), 0.f);
      v.x = fmaxf(fmaf(p.x, sb.x, hb.x) + h1x, 0.f);
      v.y = fmaxf(fmaf(p.y, sb.y, hb.y) + h1y, 0.f);
      v.z = fmaxf(fmaf(p.z, sb.z, hb.z) + h1z, 0.f);
      v.w = fmaxf(fmaf(p.w, sb.w, hb.w) + h1w, 0.f);
    }
    *reinterpret_cast<float4*>(&t_lds[nl][k]) = v;
  }
#pragma unroll
  for (int it = 0; it < 8; ++it) {
    int idx = it * 256 + tid;
    int j = idx >> 6;
    int k = idx & 63;
    w1_lds[k][j] = Wc1[(size_t)j * 64 + k];
  }
  if (tid < 64) w2_lds[tid] = Wc2[tid];
  else if (tid < 96) b1_lds[tid - 64] = bc1[tid - 64];
  else if (tid < 98) b2_lds[tid - 96] = bc2[tid - 96];
  __syncthreads();

  {
    const int tx = tid & 7, ty = tid >> 3;
    float4 a0c = make_float4(0.f, 0.f, 0.f, 0.f);
    float4 a1c = make_float4(0.f, 0.f, 0.f, 0.f);
#pragma unroll 4
    for (int k4 = 0; k4 < 16; ++k4) {
      float4 a0 = *reinterpret_cast<const float4*>(&t_lds[ty * 2 + 0][k4 * 4]);
      float4 a1 = *reinterpret_cast<const float4*>(&t_lds[ty * 2 + 1][k4 * 4]);
#pragma unroll
      for (int q = 0; q < 4; ++q) {
        float4 w = *reinterpret_cast<const float4*>(&w1_lds[k4 * 4 + q][tx * 4]);
        float a0q = reinterpret_cast<const float*>(&a0)[q];
        float a1q = reinterpret_cast<const float*>(&a1)[q];
        a0c.x = fmaf(a0q, w.x, a0c.x); a0c.y = fmaf(a0q, w.y, a0c.y);
        a0c.z = fmaf(a0q, w.z, a0c.z); a0c.w = fmaf(a0q, w.w, a0c.w);
        a1c.x = fmaf(a1q, w.x, a1c.x); a1c.y = fmaf(a1q, w.y, a1c.y);
        a1c.z = fmaf(a1q, w.z, a1c.z); a1c.w = fmaf(a1q, w.w, a1c.w);
      }
    }
    float4 b = *reinterpret_cast<const float4*>(&b1_lds[tx * 4]);
    a0c.x = fmaxf(a0c.x + b.x, 0.f); a0c.y = fmaxf(a0c.y + b.y, 0.f);
    a0c.z = fmaxf(a0c.z + b.z, 0.f); a0c.w = fmaxf(a0c.w + b.w, 0.f);
    a1c.x = fmaxf(a1c.x + b.x, 0.f); a1c.y = fmaxf(a1c.y + b.y, 0.f);
    a1c.z = fmaxf(a1c.z + b.z, 0.f); a1c.w = fmaxf(a1c.w + b.w, 0.f);
    *reinterpret_cast<float4*>(&c_lds[ty * 2 + 0][tx * 4]) = a0c;
    *reinterpret_cast<float4*>(&c_lds[ty * 2 + 1][tx * 4]) = a1c;
  }
  __syncthreads();

  if (tid < 128) {
    int nl = tid >> 1, o = tid & 1;
    int ng = nbase + nl;
    if (ng < N_NODES) {
      float s = b2_lds[o];
#pragma unroll
      for (int k = 0; k < 32; ++k) s = fmaf(c_lds[nl][k], w2_lds[o * 32 + k], s);
      out[(size_t)ng * 2 + o] = s;
    }
  }
}

// ---------------- launcher ----------------

extern "C" void kernel_launch(void* const* d_in, const int* in_sizes, int n_in,
                              void* d_out, int out_size, void* d_ws, size_t ws_size,
                              hipStream_t stream) {
  const float* x      = (const float*)d_in[0];
  const int*   ei     = (const int*)d_in[1];
  const float* ew     = (const float*)d_in[2];
  const float* W1rel  = (const float*)d_in[3];
  const float* W1root = (const float*)d_in[5];
  const float* W2rel  = (const float*)d_in[6];
  const float* W2root = (const float*)d_in[8];
  const float* W3rel  = (const float*)d_in[9];
  const float* W3root = (const float*)d_in[11];
  const float* g1  = (const float*)d_in[12];
  const float* be1 = (const float*)d_in[13];
  const float* g2  = (const float*)d_in[14];
  const float* be2 = (const float*)d_in[15];
  const float* g3  = (const float*)d_in[16];
  const float* be3 = (const float*)d_in[17];
  const float* Wc1 = (const float*)d_in[18];
  const float* bc1 = (const float*)d_in[19];
  const float* Wc2 = (const float*)d_in[20];
  const float* bc2 = (const float*)d_in[21];

  float* ws = (float*)d_ws;
  const size_t NF = (size_t)N_NODES * 64;
  float* A = ws;            // agg1 (N*32) -> agg2 (N*64) -> agg3 (N*64)
  float* B = ws + NF;       // xb(bf16) -> y2b(bf16) -> h3pre(fp32)
  float* C = ws + 2 * NF;   // h1pre fp32, live to the end
  float* E = ws + 3 * NF;   // h1preb(bf16) -> h2pre/h2act fp32 (N*128)
  float* X = ws + 5 * NF;
  float* S = X;                                 // 1024 floats: sums + sc/sh slots
  int* rowptr   = (int*)(X + 1024);             // N+2
  int* cnt      = rowptr + (N_NODES + 2);       // N
  int* cursor   = cnt + N_NODES;                // N
  int* blocksum = cursor + N_NODES;             // 128
  unsigned* col = (unsigned*)(blocksum + 128);  // E packed (w15|src17), 4B
  // S: sums1@0(128) sc1@128 sh1@192 | sums2@256(256) sc2@512 sh2@640 |
  //    sums3@768(128) sc3@896 sh3@960

  ushort* xb     = (ushort*)B;  // N*32 bf16, dead after gather1
  ushort* h1preb = (ushort*)E;  // N*64 bf16, dead after gather2
  ushort* y2b    = (ushort*)B;  // N*64 bf16, dead after gather3

  hipMemsetAsync(S, 0, 1024 * sizeof(float), stream);
  hipMemsetAsync(cnt, 0, N_NODES * sizeof(int), stream);

  const int edgeBlocks = (N_EDGES + 255) / 256;
  const int tileBlocks = (N_NODES + 63) / 64;  // 1563

  // x -> bf16 (independent of CSR build)
  cast_bf16<<<(N_NODES * 32 / 4 + 255) / 256, 256, 0, stream>>>(x, xb, N_NODES * 32 / 4);

  // CSR build (by destination)
  hist_kernel<<<edgeBlocks, 256, 0, stream>>>(ei, cnt);
  scan_phase1<<<SCAN_NB, 256, 0, stream>>>(cnt, blocksum);
  scan_phase2<<<1, 128, 0, stream>>>(blocksum, rowptr);
  scan_phase3<<<SCAN_NB, 256, 0, stream>>>(cnt, blocksum, rowptr, cursor);
  fill_kernel<<<edgeBlocks, 256, 0, stream>>>(ei, ew, cursor, col);

  // ---- layer 1 ----
  gather_d32_bf<<<(N_NODES * 4 + 255) / 256, 256, 0, stream>>>(xb, rowptr, col, A);
  gemm_node<32, 32, 64, 0, 0, 0, 1, 2><<<tileBlocks, 256, 0, stream>>>(
      A, x, W1rel, W1root, nullptr, nullptr, nullptr, C, h1preb, nullptr, S);
  bn_finalize<<<1, 128, 0, stream>>>(S, g1, be1, S + 128, S + 192, 64);

  // ---- layer 2 (BN1+relu fused into gather and gemm2 staging) ----
  gather_d64_bf<false, true><<<(N_NODES * 8 + 255) / 256, 256, 0, stream>>>(
      h1preb, rowptr, col, S + 128, S + 192, A);
  gemm_node<64, 64, 128, 0, 1, 0, 1, 0><<<tileBlocks, 256, 0, stream>>>(
      A, C, W2rel, W2root, S + 128, S + 192, nullptr, E, nullptr, nullptr, S + 256);
  bn_finalize<<<1, 128, 0, stream>>>(S + 256, g2, be2, S + 512, S + 640, 128);

  // y2b = bf16( relu(bn2(h2pre)) @ W3rel^T ); h2act -> E in place
  gemm_node<128, 0, 64, 1, 0, 0, 0, 1><<<tileBlocks, 256, 0, stream>>>(
      E, nullptr, W3rel, nullptr, S + 512, S + 640, nullptr, (float*)y2b, nullptr, E, nullptr);

  // ---- layer 3 ----
  gather_d64_bf<true, false><<<(N_NODES * 8 + 255) / 256, 256, 0, stream>>>(
      y2b, rowptr, col, nullptr, nullptr, A);
  gemm_node<128, 0, 64, 0, 0, 1, 1, 0><<<tileBlocks, 256, 0, stream>>>(
      E, nullptr, W3root, nullptr, nullptr, nullptr, A, B, nullptr, nullptr, S + 768);
  bn_finalize<<<1, 128, 0, stream>>>(S + 768, g3, be3, S + 896, S + 960, 64);

  // ---- residual + classifier ----
  final_fused<<<tileBlocks, 256, 0, stream>>>(B, C, S + 128, S + 192, S + 896, S + 960,
                                              Wc1, bc1, Wc2, bc2, (float*)d_out);
}

// Round 10
// 529.976 us; speedup vs baseline: 1.8566x; 1.0752x over previous
//
#include <hip/hip_runtime.h>

#define N_NODES 100000
#define N_EDGES 1600000
#define EPSV 1e-5f

__device__ __forceinline__ ushort f2bf(float f) {
  unsigned u = __float_as_uint(f);
  unsigned r = (u + 0x7FFFu + ((u >> 16) & 1u)) >> 16;
  return (ushort)r;
}

// ---------------- CSR-by-destination build ----------------

__global__ void hist_kernel(const int* __restrict__ ei, int* __restrict__ cnt) {
  int e = blockIdx.x * blockDim.x + threadIdx.x;
  if (e >= N_EDGES) return;
  atomicAdd(&cnt[ei[N_EDGES + e]], 1);
}

#define SCAN_BLK 1024
#define SCAN_NB ((N_NODES + SCAN_BLK - 1) / SCAN_BLK)  // 98

__global__ void scan_phase1(const int* __restrict__ cnt, int* __restrict__ blocksum) {
  __shared__ int part[256];
  int base = blockIdx.x * SCAN_BLK + threadIdx.x * 4;
  int s = 0;
#pragma unroll
  for (int i = 0; i < 4; ++i) {
    int idx = base + i;
    if (idx < N_NODES) s += cnt[idx];
  }
  part[threadIdx.x] = s;
  __syncthreads();
  for (int d = 128; d > 0; d >>= 1) {
    if (threadIdx.x < d) part[threadIdx.x] += part[threadIdx.x + d];
    __syncthreads();
  }
  if (threadIdx.x == 0) blocksum[blockIdx.x] = part[0];
}

__global__ void scan_phase2(int* __restrict__ blocksum, int* __restrict__ rowptr) {
  __shared__ int part[128];
  int tid = threadIdx.x;
  int v = (tid < SCAN_NB) ? blocksum[tid] : 0;
  part[tid] = v;
  __syncthreads();
  for (int d = 1; d < 128; d <<= 1) {
    int t = (tid >= d) ? part[tid - d] : 0;
    __syncthreads();
    part[tid] += t;
    __syncthreads();
  }
  if (tid < SCAN_NB) blocksum[tid] = part[tid] - v;  // exclusive
  if (tid == 127) rowptr[N_NODES] = part[127];
}

__global__ void scan_phase3(const int* __restrict__ cnt, const int* __restrict__ blocksum,
                            int* __restrict__ rowptr, int* __restrict__ cursor) {
  __shared__ int part[256];
  int base = blockIdx.x * SCAN_BLK + threadIdx.x * 4;
  int c[4];
  int s = 0;
#pragma unroll
  for (int i = 0; i < 4; ++i) {
    int idx = base + i;
    c[i] = (idx < N_NODES) ? cnt[idx] : 0;
    s += c[i];
  }
  part[threadIdx.x] = s;
  __syncthreads();
  int me = s;
  for (int d = 1; d < 256; d <<= 1) {
    int t = (threadIdx.x >= d) ? part[threadIdx.x - d] : 0;
    __syncthreads();
    part[threadIdx.x] += t;
    __syncthreads();
  }
  int off = blocksum[blockIdx.x] + part[threadIdx.x] - me;
#pragma unroll
  for (int i = 0; i < 4; ++i) {
    int idx = base + i;
    if (idx < N_NODES) {
      rowptr[idx] = off;
      cursor[idx] = off;
      off += c[i];
    }
  }
}

// XCD-affine fill: group g = blockIdx & 7 (round-robin -> one XCD) handles only
// destinations in [g*12500, (g+1)*12500); blocks within a group partition edges.
// All stores to a given col line then come from one XCD's L2 -> full-line writeback.
#define FILL_SUB 256  // blocks per group; grid = 8 * FILL_SUB

__global__ void fill_kernel(const int* __restrict__ ei, const float* __restrict__ ew,
                            int* __restrict__ cursor, unsigned* __restrict__ col) {
  const int g = blockIdx.x & 7;
  const int sub = blockIdx.x >> 3;
  const int lo = g * 12500;
  const int hi = lo + 12500;  // N_NODES = 8*12500 exactly
  const int EPB = (N_EDGES + FILL_SUB - 1) / FILL_SUB;  // 6250
  const int beg = sub * EPB;
  const int end = min(beg + EPB, N_EDGES);
  for (int e = beg + (int)threadIdx.x; e < end; e += (int)blockDim.x) {
    int d = ei[N_EDGES + e];
    if (d < lo || d >= hi) continue;
    int p = atomicAdd(&cursor[d], 1);
    col[p] = ((unsigned)f2bf(ew[e]) << 17) | (unsigned)ei[e];
  }
}

// ---------------- fp32 -> bf16 cast ----------------

__global__ void cast_bf16(const float* __restrict__ in, ushort* __restrict__ out, int n4) {
  int i = blockIdx.x * blockDim.x + threadIdx.x;
  if (i >= n4) return;
  float4 v = reinterpret_cast<const float4*>(in)[i];
  ushort4 o = make_ushort4(f2bf(v.x), f2bf(v.y), f2bf(v.z), f2bf(v.w));
  reinterpret_cast<ushort4*>(out)[i] = o;
}

// ---------------- gather-side segment sums (bf16 rows, 16B loads, 2x unroll) ----------------

#define SRC_OF(v) ((v) & 0x1FFFFu)
#define W_OF(v) __uint_as_float(((v) >> 17) << 16)

// 4 lanes per node, each owns 8 of 32 features (one uint4 = 8 bf16)
__global__ void gather_d32_bf(const ushort* __restrict__ xb, const int* __restrict__ rowptr,
                              const unsigned* __restrict__ col, float* __restrict__ agg) {
  int gid = blockIdx.x * blockDim.x + threadIdx.x;
  int n = gid >> 2;
  if (n >= N_NODES) return;
  int c = gid & 3;
  int beg = rowptr[n], end = rowptr[n + 1];
  float acc[8];
#pragma unroll
  for (int i = 0; i < 8; ++i) acc[i] = 0.f;
  int p = beg;
  for (; p + 1 < end; p += 2) {
    unsigned e0 = col[p], e1 = col[p + 1];
    uint4 u0 = *reinterpret_cast<const uint4*>(xb + (size_t)SRC_OF(e0) * 32 + c * 8);
    uint4 u1 = *reinterpret_cast<const uint4*>(xb + (size_t)SRC_OF(e1) * 32 + c * 8);
    unsigned a0[4] = {u0.x, u0.y, u0.z, u0.w};
    unsigned a1[4] = {u1.x, u1.y, u1.z, u1.w};
#pragma unroll
    for (int i = 0; i < 4; ++i) {
      acc[2 * i]     += __uint_as_float(a0[i] << 16) + __uint_as_float(a1[i] << 16);
      acc[2 * i + 1] += __uint_as_float(a0[i] & 0xFFFF0000u) +
                        __uint_as_float(a1[i] & 0xFFFF0000u);
    }
  }
  if (p < end) {
    unsigned e0 = col[p];
    uint4 u0 = *reinterpret_cast<const uint4*>(xb + (size_t)SRC_OF(e0) * 32 + c * 8);
    unsigned a0[4] = {u0.x, u0.y, u0.z, u0.w};
#pragma unroll
    for (int i = 0; i < 4; ++i) {
      acc[2 * i]     += __uint_as_float(a0[i] << 16);
      acc[2 * i + 1] += __uint_as_float(a0[i] & 0xFFFF0000u);
    }
  }
  float* op = agg + (size_t)n * 32 + c * 8;
  *reinterpret_cast<float4*>(op)     = make_float4(acc[0], acc[1], acc[2], acc[3]);
  *reinterpret_cast<float4*>(op + 4) = make_float4(acc[4], acc[5], acc[6], acc[7]);
}

// 8 lanes per node, each owns 8 of 64 features.
// TRANS: apply per-feature relu(fma(v,sc,sh)) to each loaded element (BN1 on the fly)
template <bool WEIGHTED, bool TRANS>
__global__ void gather_d64_bf(const ushort* __restrict__ hb, const int* __restrict__ rowptr,
                              const unsigned* __restrict__ col,
                              const float* __restrict__ sc, const float* __restrict__ sh,
                              float* __restrict__ agg) {
  int gid = blockIdx.x * blockDim.x + threadIdx.x;
  int n = gid >> 3;
  if (n >= N_NODES) return;
  int c = gid & 7;
  int beg = rowptr[n], end = rowptr[n + 1];
  float sc8[8], sh8[8];
  if (TRANS) {
#pragma unroll
    for (int i = 0; i < 8; ++i) {
      sc8[i] = sc[c * 8 + i];
      sh8[i] = sh[c * 8 + i];
    }
  }
  float acc[8];
#pragma unroll
  for (int i = 0; i < 8; ++i) acc[i] = 0.f;

  auto body = [&](unsigned ev, const uint4& u) {
    float w = WEIGHTED ? W_OF(ev) : 1.f;
    unsigned uu[4] = {u.x, u.y, u.z, u.w};
#pragma unroll
    for (int i = 0; i < 4; ++i) {
      float lo = __uint_as_float(uu[i] << 16);
      float hi = __uint_as_float(uu[i] & 0xFFFF0000u);
      if (TRANS) {
        lo = fmaxf(fmaf(lo, sc8[2 * i], sh8[2 * i]), 0.f);
        hi = fmaxf(fmaf(hi, sc8[2 * i + 1], sh8[2 * i + 1]), 0.f);
      }
      if (WEIGHTED) {
        acc[2 * i]     = fmaf(lo, w, acc[2 * i]);
        acc[2 * i + 1] = fmaf(hi, w, acc[2 * i + 1]);
      } else {
        acc[2 * i]     += lo;
        acc[2 * i + 1] += hi;
      }
    }
  };

  int p = beg;
  for (; p + 1 < end; p += 2) {
    unsigned e0 = col[p], e1 = col[p + 1];
    uint4 u0 = *reinterpret_cast<const uint4*>(hb + (size_t)SRC_OF(e0) * 64 + c * 8);
    uint4 u1 = *reinterpret_cast<const uint4*>(hb + (size_t)SRC_OF(e1) * 64 + c * 8);
    body(e0, u0);
    body(e1, u1);
  }
  if (p < end) {
    unsigned e0 = col[p];
    uint4 u0 = *reinterpret_cast<const uint4*>(hb + (size_t)SRC_OF(e0) * 64 + c * 8);
    body(e0, u0);
  }
  float* op = agg + (size_t)n * 64 + c * 8;
  *reinterpret_cast<float4*>(op)     = make_float4(acc[0], acc[1], acc[2], acc[3]);
  *reinterpret_cast<float4*>(op + 4) = make_float4(acc[4], acc[5], acc[6], acc[7]);
}

// ---------------- LDS-tiled node GEMM with fused BN stats (atomic) ----------------
// out[M x DO] = [A1 | A2] @ [W1 ; W2]^T
// TA1: BN+relu A1 during staging (sc,sh indexed by k), write transformed back to h2act
// TA2: BN+relu A2 during staging (sc,sh indexed by k-K1), no write-back
// RADD: out += R before store/stats
// STATS: per-block {sum,sumsq} atomically added into sums[2*DO]
// OUTM: 0 = fp32, 1 = bf16, 2 = both (fp32 -> out, bf16 -> outb)

template <int K1, int K2, int DO, int TA1, int TA2, int RADD, int STATS, int OUTM>
__global__ __launch_bounds__(256) void gemm_node(
    const float* __restrict__ A1, const float* __restrict__ A2,
    const float* __restrict__ W1, const float* __restrict__ W2,
    const float* __restrict__ sc, const float* __restrict__ sh,
    const float* __restrict__ R, float* __restrict__ out, ushort* __restrict__ outb,
    float* h2act, float* __restrict__ sums) {
  constexpr int K = K1 + K2;
  constexpr int NC = K / 64;
  constexpr int NJB = DO / 64;
  __shared__ __align__(16) float A_lds[64][68];
  __shared__ __align__(16) float W_lds[64][DO + 4];

  const int tid = threadIdx.x;
  const int tx = tid & 15, ty = tid >> 4;
  const int nbase = blockIdx.x * 64;

  float4 acc[4][NJB];
#pragma unroll
  for (int i = 0; i < 4; ++i)
#pragma unroll
    for (int jb = 0; jb < NJB; ++jb) acc[i][jb] = make_float4(0.f, 0.f, 0.f, 0.f);

#pragma unroll 1
  for (int c = 0; c < NC; ++c) {
    const int kb = c * 64;
    if (c) __syncthreads();
#pragma unroll
    for (int it = 0; it < 4; ++it) {
      int idx = it * 256 + tid;
      int nl = idx >> 4;
      int kq = (idx & 15) * 4;
      int k = kb + kq;
      int ng = nbase + nl;
      float4 v = make_float4(0.f, 0.f, 0.f, 0.f);
      bool isA1 = (K2 == 0) || (k < K1);
      if (ng < N_NODES) {
        if (isA1)
          v = *reinterpret_cast<const float4*>(A1 + (size_t)ng * K1 + k);
        else
          v = *reinterpret_cast<const float4*>(A2 + (size_t)ng * K2 + (k - K1));
      }
      if constexpr (TA1) {
        if (isA1) {
          float4 s4 = *reinterpret_cast<const float4*>(sc + k);
          float4 h4 = *reinterpret_cast<const float4*>(sh + k);
          v.x = fmaxf(fmaf(v.x, s4.x, h4.x), 0.f);
          v.y = fmaxf(fmaf(v.y, s4.y, h4.y), 0.f);
          v.z = fmaxf(fmaf(v.z, s4.z, h4.z), 0.f);
          v.w = fmaxf(fmaf(v.w, s4.w, h4.w), 0.f);
          if (ng < N_NODES)
            *reinterpret_cast<float4*>(h2act + (size_t)ng * K1 + k) = v;
        }
      }
      if constexpr (TA2 && K2 > 0) {
        if (!isA1) {
          float4 s4 = *reinterpret_cast<const float4*>(sc + (k - K1));
          float4 h4 = *reinterpret_cast<const float4*>(sh + (k - K1));
          v.x = fmaxf(fmaf(v.x, s4.x, h4.x), 0.f);
          v.y = fmaxf(fmaf(v.y, s4.y, h4.y), 0.f);
          v.z = fmaxf(fmaf(v.z, s4.z, h4.z), 0.f);
          v.w = fmaxf(fmaf(v.w, s4.w, h4.w), 0.f);
        }
      }
      *reinterpret_cast<float4*>(&A_lds[nl][kq]) = v;
    }
#pragma unroll
    for (int it = 0; it < DO / 4; ++it) {
      int idx = it * 256 + tid;
      int j = idx >> 6;
      int kl = idx & 63;
      int k = kb + kl;
      float w;
      if (K2 == 0 || k < K1) w = W1[(size_t)j * K1 + k];
      else w = W2[(size_t)j * K2 + (k - K1)];
      W_lds[kl][j] = w;
    }
    __syncthreads();
#pragma unroll 4
    for (int k4 = 0; k4 < 16; ++k4) {
      float4 a[4];
#pragma unroll
      for (int i = 0; i < 4; ++i)
        a[i] = *reinterpret_cast<const float4*>(&A_lds[ty * 4 + i][k4 * 4]);
#pragma unroll
      for (int q = 0; q < 4; ++q) {
#pragma unroll
        for (int jb = 0; jb < NJB; ++jb) {
          float4 w = *reinterpret_cast<const float4*>(&W_lds[k4 * 4 + q][jb * 64 + tx * 4]);
#pragma unroll
          for (int i = 0; i < 4; ++i) {
            float av = reinterpret_cast<const float*>(&a[i])[q];
            acc[i][jb].x = fmaf(av, w.x, acc[i][jb].x);
            acc[i][jb].y = fmaf(av, w.y, acc[i][jb].y);
            acc[i][jb].z = fmaf(av, w.z, acc[i][jb].z);
            acc[i][jb].w = fmaf(av, w.w, acc[i][jb].w);
          }
        }
      }
    }
  }
  // ---- R add (into acc so stats see it) + output ----
#pragma unroll
  for (int i = 0; i < 4; ++i) {
    int ng = nbase + ty * 4 + i;
    if (ng >= N_NODES) continue;
#pragma unroll
    for (int jb = 0; jb < NJB; ++jb) {
      if constexpr (RADD) {
        float4 rr = *reinterpret_cast<const float4*>(R + (size_t)ng * DO + jb * 64 + tx * 4);
        acc[i][jb].x += rr.x; acc[i][jb].y += rr.y;
        acc[i][jb].z += rr.z; acc[i][jb].w += rr.w;
      }
      size_t off = (size_t)ng * DO + jb * 64 + tx * 4;
      if constexpr (OUTM == 1) {
        ushort4 o = make_ushort4(f2bf(acc[i][jb].x), f2bf(acc[i][jb].y),
                                 f2bf(acc[i][jb].z), f2bf(acc[i][jb].w));
        *reinterpret_cast<ushort4*>((ushort*)out + off) = o;
      } else {
        *reinterpret_cast<float4*>(out + off) = acc[i][jb];
        if constexpr (OUTM == 2) {
          ushort4 o = make_ushort4(f2bf(acc[i][jb].x), f2bf(acc[i][jb].y),
                                   f2bf(acc[i][jb].z), f2bf(acc[i][jb].w));
          *reinterpret_cast<ushort4*>(outb + off) = o;
        }
      }
    }
  }
  // ---- fused BN stats: block-local LDS reduce, then one atomic per column ----
  if constexpr (STATS) {
    __syncthreads();  // done reading A_lds/W_lds; safe to reuse
    float* sums_l = &A_lds[0][0];  // [16][DO]
    float* sq_l = &W_lds[0][0];    // [16][DO]
#pragma unroll
    for (int jb = 0; jb < NJB; ++jb) {
      float4 s = make_float4(0.f, 0.f, 0.f, 0.f);
      float4 q = make_float4(0.f, 0.f, 0.f, 0.f);
#pragma unroll
      for (int i = 0; i < 4; ++i) {
        if (nbase + ty * 4 + i < N_NODES) {
          float4 v = acc[i][jb];
          s.x += v.x; s.y += v.y; s.z += v.z; s.w += v.w;
          q.x = fmaf(v.x, v.x, q.x); q.y = fmaf(v.y, v.y, q.y);
          q.z = fmaf(v.z, v.z, q.z); q.w = fmaf(v.w, v.w, q.w);
        }
      }
      *reinterpret_cast<float4*>(&sums_l[ty * DO + jb * 64 + tx * 4]) = s;
      *reinterpret_cast<float4*>(&sq_l[ty * DO + jb * 64 + tx * 4]) = q;
    }
    __syncthreads();
    if (tid < DO) {
      float s = 0.f, q = 0.f;
#pragma unroll
      for (int t = 0; t < 16; ++t) {
        s += sums_l[t * DO + tid];
        q += sq_l[t * DO + tid];
      }
      unsafeAtomicAdd(&sums[tid], s);
      unsafeAtomicAdd(&sums[DO + tid], q);
    }
  }
}

// ---------------- BN finalize ----------------

__global__ void bn_finalize(const float* __restrict__ sums, const float* __restrict__ g,
                            const float* __restrict__ be, float* __restrict__ sc,
                            float* __restrict__ sh, int D) {
  int j = threadIdx.x;
  if (j >= D) return;
  const float invN = 1.f / (float)N_NODES;
  float mean = sums[j] * invN;
  float var = sums[D + j] * invN - mean * mean;
  float r = rsqrtf(var + EPSV);
  float scale = g[j] * r;
  sc[j] = scale;
  sh[j] = be[j] - mean * scale;
}

// ---------------- fused residual + classifier ----------------
// h1 = relu(bn1(h1pre)); t = relu(bn3(h3p) + h1); c = relu(t@Wc1^T+bc1); out = c@Wc2^T+bc2

__global__ __launch_bounds__(256) void final_fused(
    const float* __restrict__ h3p, const float* __restrict__ h1p,
    const float* __restrict__ sc1, const float* __restrict__ sh1,
    const float* __restrict__ sc3, const float* __restrict__ sh3,
    const float* __restrict__ Wc1, const float* __restrict__ bc1,
    const float* __restrict__ Wc2, const float* __restrict__ bc2,
    float* __restrict__ out) {
  __shared__ __align__(16) float t_lds[64][68];
  __shared__ __align__(16) float w1_lds[64][36];
  __shared__ __align__(16) float c_lds[64][36];
  __shared__ __align__(16) float w2_lds[64];
  __shared__ __align__(16) float b1_lds[32];
  __shared__ float b2_lds[2];
  const int tid = threadIdx.x;
  const int nbase = blockIdx.x * 64;

#pragma unroll
  for (int it = 0; it < 4; ++it) {
    int idx = it * 256 + tid;
    int nl = idx >> 4;
    int k = (idx & 15) * 4;
    int ng = nbase + nl;
    float4 v = make_float4(0.f, 0.f, 0.f, 0.f);
    if (ng < N_NODES) {
      float4 p = *reinterpret_cast<const float4*>(h3p + (size_t)ng * 64 + k);
      float4 u = *reinterpret_cast<const float4*>(h1p + (size_t)ng * 64 + k);
      float4 sa = *reinterpret_cast<const float4*>(sc1 + k);
      float4 ha = *reinterpret_cast<const float4*>(sh1 + k);
      float4 sb = *reinterpret_cast<const float4*>(sc3 + k);
      float4 hb = *reinterpret_cast<const float4*>(sh3 + k);
      float h1x = fmaxf(fmaf(u.x, sa.x, ha.x), 0.f);
      float h1y = fmaxf(fmaf(u.y, sa.y, ha.y), 0.f);
      float h1z = fmaxf(fmaf(u.z, sa.z, ha.z), 0.f);
      float h1w = fmaxf(fmaf(u.w, sa.w, ha.w), 0.f);
      v.x = fmaxf(fmaf(p.x, sb.x, hb.x) + h1x, 0.f);
      v.y = fmaxf(fmaf(p.y, sb.y, hb.y) + h1y, 0.f);
      v.z = fmaxf(fmaf(p.z, sb.z, hb.z) + h1z, 0.f);
      v.w = fmaxf(fmaf(p.w, sb.w, hb.w) + h1w, 0.f);
    }
    *reinterpret_cast<float4*>(&t_lds[nl][k]) = v;
  }
#pragma unroll
  for (int it = 0; it < 8; ++it) {
    int idx = it * 256 + tid;
    int j = idx >> 6;
    int k = idx & 63;
    w1_lds[k][j] = Wc1[(size_t)j * 64 + k];
  }
  if (tid < 64) w2_lds[tid] = Wc2[tid];
  else if (tid < 96) b1_lds[tid - 64] = bc1[tid - 64];
  else if (tid < 98) b2_lds[tid - 96] = bc2[tid - 96];
  __syncthreads();

  {
    const int tx = tid & 7, ty = tid >> 3;
    float4 a0c = make_float4(0.f, 0.f, 0.f, 0.f);
    float4 a1c = make_float4(0.f, 0.f, 0.f, 0.f);
#pragma unroll 4
    for (int k4 = 0; k4 < 16; ++k4) {
      float4 a0 = *reinterpret_cast<const float4*>(&t_lds[ty * 2 + 0][k4 * 4]);
      float4 a1 = *reinterpret_cast<const float4*>(&t_lds[ty * 2 + 1][k4 * 4]);
#pragma unroll
      for (int q = 0; q < 4; ++q) {
        float4 w = *reinterpret_cast<const float4*>(&w1_lds[k4 * 4 + q][tx * 4]);
        float a0q = reinterpret_cast<const float*>(&a0)[q];
        float a1q = reinterpret_cast<const float*>(&a1)[q];
        a0c.x = fmaf(a0q, w.x, a0c.x); a0c.y = fmaf(a0q, w.y, a0c.y);
        a0c.z = fmaf(a0q, w.z, a0c.z); a0c.w = fmaf(a0q, w.w, a0c.w);
        a1c.x = fmaf(a1q, w.x, a1c.x); a1c.y = fmaf(a1q, w.y, a1c.y);
        a1c.z = fmaf(a1q, w.z, a1c.z); a1c.w = fmaf(a1q, w.w, a1c.w);
      }
    }
    float4 b = *reinterpret_cast<const float4*>(&b1_lds[tx * 4]);
    a0c.x = fmaxf(a0c.x + b.x, 0.f); a0c.y = fmaxf(a0c.y + b.y, 0.f);
    a0c.z = fmaxf(a0c.z + b.z, 0.f); a0c.w = fmaxf(a0c.w + b.w, 0.f);
    a1c.x = fmaxf(a1c.x + b.x, 0.f); a1c.y = fmaxf(a1c.y + b.y, 0.f);
    a1c.z = fmaxf(a1c.z + b.z, 0.f); a1c.w = fmaxf(a1c.w + b.w, 0.f);
    *reinterpret_cast<float4*>(&c_lds[ty * 2 + 0][tx * 4]) = a0c;
    *reinterpret_cast<float4*>(&c_lds[ty * 2 + 1][tx * 4]) = a1c;
  }
  __syncthreads();

  if (tid < 128) {
    int nl = tid >> 1, o = tid & 1;
    int ng = nbase + nl;
    if (ng < N_NODES) {
      float s = b2_lds[o];
#pragma unroll
      for (int k = 0; k < 32; ++k) s = fmaf(c_lds[nl][k], w2_lds[o * 32 + k], s);
      out[(size_t)ng * 2 + o] = s;
    }
  }
}

// ---------------- launcher ----------------

extern "C" void kernel_launch(void* const* d_in, const int* in_sizes, int n_in,
                              void* d_out, int out_size, void* d_ws, size_t ws_size,
                              hipStream_t stream) {
  const float* x      = (const float*)d_in[0];
  const int*   ei     = (const int*)d_in[1];
  const float* ew     = (const float*)d_in[2];
  const float* W1rel  = (const float*)d_in[3];
  const float* W1root = (const float*)d_in[5];
  const float* W2rel  = (const float*)d_in[6];
  const float* W2root = (const float*)d_in[8];
  const float* W3rel  = (const float*)d_in[9];
  const float* W3root = (const float*)d_in[11];
  const float* g1  = (const float*)d_in[12];
  const float* be1 = (const float*)d_in[13];
  const float* g2  = (const float*)d_in[14];
  const float* be2 = (const float*)d_in[15];
  const float* g3  = (const float*)d_in[16];
  const float* be3 = (const float*)d_in[17];
  const float* Wc1 = (const float*)d_in[18];
  const float* bc1 = (const float*)d_in[19];
  const float* Wc2 = (const float*)d_in[20];
  const float* bc2 = (const float*)d_in[21];

  float* ws = (float*)d_ws;
  const size_t NF = (size_t)N_NODES * 64;
  float* A = ws;            // agg1 (N*32) -> agg2 (N*64) -> agg3 (N*64)
  float* B = ws + NF;       // xb(bf16) -> y2b(bf16) -> h3pre(fp32)
  float* C = ws + 2 * NF;   // h1pre fp32, live to the end
  float* E = ws + 3 * NF;   // h1preb(bf16) -> h2pre/h2act fp32 (N*128)
  float* X = ws + 5 * NF;
  float* S = X;                                 // 1024 floats: sums + sc/sh slots
  int* rowptr   = (int*)(X + 1024);             // N+2
  int* cnt      = rowptr + (N_NODES + 2);       // N
  int* cursor   = cnt + N_NODES;                // N
  int* blocksum = cursor + N_NODES;             // 128
  unsigned* col = (unsigned*)(blocksum + 128);  // E packed (w15|src17), 4B
  // S: sums1@0(128) sc1@128 sh1@192 | sums2@256(256) sc2@512 sh2@640 |
  //    sums3@768(128) sc3@896 sh3@960

  ushort* xb     = (ushort*)B;  // N*32 bf16, dead after gather1
  ushort* h1preb = (ushort*)E;  // N*64 bf16, dead after gather2
  ushort* y2b    = (ushort*)B;  // N*64 bf16, dead after gather3

  hipMemsetAsync(S, 0, 1024 * sizeof(float), stream);
  hipMemsetAsync(cnt, 0, N_NODES * sizeof(int), stream);

  const int edgeBlocks = (N_EDGES + 255) / 256;
  const int tileBlocks = (N_NODES + 63) / 64;  // 1563

  // x -> bf16 (independent of CSR build)
  cast_bf16<<<(N_NODES * 32 / 4 + 255) / 256, 256, 0, stream>>>(x, xb, N_NODES * 32 / 4);

  // CSR build (by destination)
  hist_kernel<<<edgeBlocks, 256, 0, stream>>>(ei, cnt);
  scan_phase1<<<SCAN_NB, 256, 0, stream>>>(cnt, blocksum);
  scan_phase2<<<1, 128, 0, stream>>>(blocksum, rowptr);
  scan_phase3<<<SCAN_NB, 256, 0, stream>>>(cnt, blocksum, rowptr, cursor);
  fill_kernel<<<8 * FILL_SUB, 256, 0, stream>>>(ei, ew, cursor, col);

  // ---- layer 1 ----
  gather_d32_bf<<<(N_NODES * 4 + 255) / 256, 256, 0, stream>>>(xb, rowptr, col, A);
  gemm_node<32, 32, 64, 0, 0, 0, 1, 2><<<tileBlocks, 256, 0, stream>>>(
      A, x, W1rel, W1root, nullptr, nullptr, nullptr, C, h1preb, nullptr, S);
  bn_finalize<<<1, 128, 0, stream>>>(S, g1, be1, S + 128, S + 192, 64);

  // ---- layer 2 (BN1+relu fused into gather and gemm2 staging) ----
  gather_d64_bf<false, true><<<(N_NODES * 8 + 255) / 256, 256, 0, stream>>>(
      h1preb, rowptr, col, S + 128, S + 192, A);
  gemm_node<64, 64, 128, 0, 1, 0, 1, 0><<<tileBlocks, 256, 0, stream>>>(
      A, C, W2rel, W2root, S + 128, S + 192, nullptr, E, nullptr, nullptr, S + 256);
  bn_finalize<<<1, 128, 0, stream>>>(S + 256, g2, be2, S + 512, S + 640, 128);

  // y2b = bf16( relu(bn2(h2pre)) @ W3rel^T ); h2act -> E in place
  gemm_node<128, 0, 64, 1, 0, 0, 0, 1><<<tileBlocks, 256, 0, stream>>>(
      E, nullptr, W3rel, nullptr, S + 512, S + 640, nullptr, (float*)y2b, nullptr, E, nullptr);

  // ---- layer 3 ----
  gather_d64_bf<true, false><<<(N_NODES * 8 + 255) / 256, 256, 0, stream>>>(
      y2b, rowptr, col, nullptr, nullptr, A);
  gemm_node<128, 0, 64, 0, 0, 1, 1, 0><<<tileBlocks, 256, 0, stream>>>(
      E, nullptr, W3root, nullptr, nullptr, nullptr, A, B, nullptr, nullptr, S + 768);
  bn_finalize<<<1, 128, 0, stream>>>(S + 768, g3, be3, S + 896, S + 960, 64);

  // ---- residual + classifier ----
  final_fused<<<tileBlocks, 256, 0, stream>>>(B, C, S + 128, S + 192, S + 896, S + 960,
                                              Wc1, bc1, Wc2, bc2, (float*)d_out);
}

// Round 11
// 479.677 us; speedup vs baseline: 2.0512x; 1.1049x over previous
//
#include <hip/hip_runtime.h>

#define N_NODES 100000
#define N_EDGES 1600000
#define EPSV 1e-5f

__device__ __forceinline__ ushort f2bf(float f) {
  unsigned u = __float_as_uint(f);
  unsigned r = (u + 0x7FFFu + ((u >> 16) & 1u)) >> 16;
  return (ushort)r;
}

// ---------------- CSR-by-destination build ----------------

__global__ void hist_kernel(const int* __restrict__ ei, int* __restrict__ cnt) {
  int e = blockIdx.x * blockDim.x + threadIdx.x;
  if (e >= N_EDGES) return;
  atomicAdd(&cnt[ei[N_EDGES + e]], 1);
}

#define SCAN_BLK 1024
#define SCAN_NB ((N_NODES + SCAN_BLK - 1) / SCAN_BLK)  // 98

__global__ void scan_phase1(const int* __restrict__ cnt, int* __restrict__ blocksum) {
  __shared__ int part[256];
  int base = blockIdx.x * SCAN_BLK + threadIdx.x * 4;
  int s = 0;
#pragma unroll
  for (int i = 0; i < 4; ++i) {
    int idx = base + i;
    if (idx < N_NODES) s += cnt[idx];
  }
  part[threadIdx.x] = s;
  __syncthreads();
  for (int d = 128; d > 0; d >>= 1) {
    if (threadIdx.x < d) part[threadIdx.x] += part[threadIdx.x + d];
    __syncthreads();
  }
  if (threadIdx.x == 0) blocksum[blockIdx.x] = part[0];
}

__global__ void scan_phase2(int* __restrict__ blocksum, int* __restrict__ rowptr) {
  __shared__ int part[128];
  int tid = threadIdx.x;
  int v = (tid < SCAN_NB) ? blocksum[tid] : 0;
  part[tid] = v;
  __syncthreads();
  for (int d = 1; d < 128; d <<= 1) {
    int t = (tid >= d) ? part[tid - d] : 0;
    __syncthreads();
    part[tid] += t;
    __syncthreads();
  }
  if (tid < SCAN_NB) blocksum[tid] = part[tid] - v;  // exclusive
  if (tid == 127) rowptr[N_NODES] = part[127];
}

__global__ void scan_phase3(const int* __restrict__ cnt, const int* __restrict__ blocksum,
                            int* __restrict__ rowptr, int* __restrict__ cursor) {
  __shared__ int part[256];
  int base = blockIdx.x * SCAN_BLK + threadIdx.x * 4;
  int c[4];
  int s = 0;
#pragma unroll
  for (int i = 0; i < 4; ++i) {
    int idx = base + i;
    c[i] = (idx < N_NODES) ? cnt[idx] : 0;
    s += c[i];
  }
  part[threadIdx.x] = s;
  __syncthreads();
  int me = s;
  for (int d = 1; d < 256; d <<= 1) {
    int t = (threadIdx.x >= d) ? part[threadIdx.x - d] : 0;
    __syncthreads();
    part[threadIdx.x] += t;
    __syncthreads();
  }
  int off = blocksum[blockIdx.x] + part[threadIdx.x] - me;
#pragma unroll
  for (int i = 0; i < 4; ++i) {
    int idx = base + i;
    if (idx < N_NODES) {
      rowptr[idx] = off;
      cursor[idx] = off;
      off += c[i];
    }
  }
}

// XCD-affine fill: group g = blockIdx & 7 handles dsts in [g*12500,(g+1)*12500)
#define FILL_SUB 256

__global__ void fill_kernel(const int* __restrict__ ei, const float* __restrict__ ew,
                            int* __restrict__ cursor, unsigned* __restrict__ col) {
  const int g = blockIdx.x & 7;
  const int sub = blockIdx.x >> 3;
  const int lo = g * 12500;
  const int hi = lo + 12500;
  const int EPB = (N_EDGES + FILL_SUB - 1) / FILL_SUB;
  const int beg = sub * EPB;
  const int end = min(beg + EPB, N_EDGES);
  for (int e = beg + (int)threadIdx.x; e < end; e += (int)blockDim.x) {
    int d = ei[N_EDGES + e];
    if (d < lo || d >= hi) continue;
    int p = atomicAdd(&cursor[d], 1);
    col[p] = ((unsigned)f2bf(ew[e]) << 17) | (unsigned)ei[e];
  }
}

// ---------------- fp32 -> bf16 cast ----------------

__global__ void cast_bf16(const float* __restrict__ in, ushort* __restrict__ out, int n4) {
  int i = blockIdx.x * blockDim.x + threadIdx.x;
  if (i >= n4) return;
  float4 v = reinterpret_cast<const float4*>(in)[i];
  ushort4 o = make_ushort4(f2bf(v.x), f2bf(v.y), f2bf(v.z), f2bf(v.w));
  reinterpret_cast<ushort4*>(out)[i] = o;
}

// ---------------- weight pre-transpose (k-major concat layouts) ----------------
// Wt layout: Wt1 [64][64] @0 (k<32: W1rel, else W1root)
//            Wt2 [128][128] @4096 (k<64: W2rel, else W2root)
//            Wt3r [128][64] @20480 (W3rel)
//            Wt3o [128][64] @28672 (W3root)   total 36864 floats

__global__ void wtrans_kernel(const float* __restrict__ W1rel, const float* __restrict__ W1root,
                              const float* __restrict__ W2rel, const float* __restrict__ W2root,
                              const float* __restrict__ W3rel, const float* __restrict__ W3root,
                              float* __restrict__ Wt) {
  int i = blockIdx.x * blockDim.x + threadIdx.x;
  if (i >= 36864) return;
  float v;
  if (i < 4096) {
    int k = i >> 6, j = i & 63;
    v = (k < 32) ? W1rel[j * 32 + k] : W1root[j * 32 + (k - 32)];
  } else if (i < 20480) {
    int r = i - 4096;
    int k = r >> 7, j = r & 127;
    v = (k < 64) ? W2rel[j * 64 + k] : W2root[j * 64 + (k - 64)];
  } else if (i < 28672) {
    int r = i - 20480;
    int k = r >> 6, j = r & 63;
    v = W3rel[j * 128 + k];
  } else {
    int r = i - 28672;
    int k = r >> 6, j = r & 63;
    v = W3root[j * 128 + k];
  }
  Wt[i] = v;
}

// ---------------- gather-side segment sums (bf16 rows, 16B loads, 2x unroll) ----------------

#define SRC_OF(v) ((v) & 0x1FFFFu)
#define W_OF(v) __uint_as_float(((v) >> 17) << 16)

__global__ void gather_d32_bf(const ushort* __restrict__ xb, const int* __restrict__ rowptr,
                              const unsigned* __restrict__ col, float* __restrict__ agg) {
  int gid = blockIdx.x * blockDim.x + threadIdx.x;
  int n = gid >> 2;
  if (n >= N_NODES) return;
  int c = gid & 3;
  int beg = rowptr[n], end = rowptr[n + 1];
  float acc[8];
#pragma unroll
  for (int i = 0; i < 8; ++i) acc[i] = 0.f;
  int p = beg;
  for (; p + 1 < end; p += 2) {
    unsigned e0 = col[p], e1 = col[p + 1];
    uint4 u0 = *reinterpret_cast<const uint4*>(xb + (size_t)SRC_OF(e0) * 32 + c * 8);
    uint4 u1 = *reinterpret_cast<const uint4*>(xb + (size_t)SRC_OF(e1) * 32 + c * 8);
    unsigned a0[4] = {u0.x, u0.y, u0.z, u0.w};
    unsigned a1[4] = {u1.x, u1.y, u1.z, u1.w};
#pragma unroll
    for (int i = 0; i < 4; ++i) {
      acc[2 * i]     += __uint_as_float(a0[i] << 16) + __uint_as_float(a1[i] << 16);
      acc[2 * i + 1] += __uint_as_float(a0[i] & 0xFFFF0000u) +
                        __uint_as_float(a1[i] & 0xFFFF0000u);
    }
  }
  if (p < end) {
    unsigned e0 = col[p];
    uint4 u0 = *reinterpret_cast<const uint4*>(xb + (size_t)SRC_OF(e0) * 32 + c * 8);
    unsigned a0[4] = {u0.x, u0.y, u0.z, u0.w};
#pragma unroll
    for (int i = 0; i < 4; ++i) {
      acc[2 * i]     += __uint_as_float(a0[i] << 16);
      acc[2 * i + 1] += __uint_as_float(a0[i] & 0xFFFF0000u);
    }
  }
  float* op = agg + (size_t)n * 32 + c * 8;
  *reinterpret_cast<float4*>(op)     = make_float4(acc[0], acc[1], acc[2], acc[3]);
  *reinterpret_cast<float4*>(op + 4) = make_float4(acc[4], acc[5], acc[6], acc[7]);
}

template <bool WEIGHTED, bool TRANS>
__global__ void gather_d64_bf(const ushort* __restrict__ hb, const int* __restrict__ rowptr,
                              const unsigned* __restrict__ col,
                              const float* __restrict__ sc, const float* __restrict__ sh,
                              float* __restrict__ agg) {
  int gid = blockIdx.x * blockDim.x + threadIdx.x;
  int n = gid >> 3;
  if (n >= N_NODES) return;
  int c = gid & 7;
  int beg = rowptr[n], end = rowptr[n + 1];
  float sc8[8], sh8[8];
  if (TRANS) {
#pragma unroll
    for (int i = 0; i < 8; ++i) {
      sc8[i] = sc[c * 8 + i];
      sh8[i] = sh[c * 8 + i];
    }
  }
  float acc[8];
#pragma unroll
  for (int i = 0; i < 8; ++i) acc[i] = 0.f;

  auto body = [&](unsigned ev, const uint4& u) {
    float w = WEIGHTED ? W_OF(ev) : 1.f;
    unsigned uu[4] = {u.x, u.y, u.z, u.w};
#pragma unroll
    for (int i = 0; i < 4; ++i) {
      float lo = __uint_as_float(uu[i] << 16);
      float hi = __uint_as_float(uu[i] & 0xFFFF0000u);
      if (TRANS) {
        lo = fmaxf(fmaf(lo, sc8[2 * i], sh8[2 * i]), 0.f);
        hi = fmaxf(fmaf(hi, sc8[2 * i + 1], sh8[2 * i + 1]), 0.f);
      }
      if (WEIGHTED) {
        acc[2 * i]     = fmaf(lo, w, acc[2 * i]);
        acc[2 * i + 1] = fmaf(hi, w, acc[2 * i + 1]);
      } else {
        acc[2 * i]     += lo;
        acc[2 * i + 1] += hi;
      }
    }
  };

  int p = beg;
  for (; p + 1 < end; p += 2) {
    unsigned e0 = col[p], e1 = col[p + 1];
    uint4 u0 = *reinterpret_cast<const uint4*>(hb + (size_t)SRC_OF(e0) * 64 + c * 8);
    uint4 u1 = *reinterpret_cast<const uint4*>(hb + (size_t)SRC_OF(e1) * 64 + c * 8);
    body(e0, u0);
    body(e1, u1);
  }
  if (p < end) {
    unsigned e0 = col[p];
    uint4 u0 = *reinterpret_cast<const uint4*>(hb + (size_t)SRC_OF(e0) * 64 + c * 8);
    body(e0, u0);
  }
  float* op = agg + (size_t)n * 64 + c * 8;
  *reinterpret_cast<float4*>(op)     = make_float4(acc[0], acc[1], acc[2], acc[3]);
  *reinterpret_cast<float4*>(op + 4) = make_float4(acc[4], acc[5], acc[6], acc[7]);
}

// ---------------- LDS-tiled node GEMM (BK=32, pre-transposed W, occupancy-capped) ----
// out[M x DO] = [A1 | A2] @ Wt  (Wt is k-major [K][DO])
// TA1/TA2: BN+relu on A1/A2 during staging; TA1 also writes transformed A1 to h2act.
// RADD: out += R.  STATS: atomic per-feature {sum,sumsq} into sums[2*DO].
// OUTM: 0 fp32, 1 bf16, 2 both.

template <int K1, int K2, int DO, int TA1, int TA2, int RADD, int STATS, int OUTM>
__global__ __launch_bounds__(256, 4) void gemm_node(
    const float* __restrict__ A1, const float* __restrict__ A2,
    const float* __restrict__ Wt,
    const float* __restrict__ sc, const float* __restrict__ sh,
    const float* __restrict__ R, float* __restrict__ out, ushort* __restrict__ outb,
    float* h2act, float* __restrict__ sums) {
  constexpr int K = K1 + K2;
  constexpr int NC = K / 32;
  constexpr int NJB = DO / 64;
  __shared__ __align__(16) float A_lds[64][36];
  __shared__ __align__(16) float W_lds[32][DO];

  const int tid = threadIdx.x;
  const int tx = tid & 15, ty = tid >> 4;
  const int nbase = blockIdx.x * 64;

  float4 acc[4][NJB];
#pragma unroll
  for (int i = 0; i < 4; ++i)
#pragma unroll
    for (int jb = 0; jb < NJB; ++jb) acc[i][jb] = make_float4(0.f, 0.f, 0.f, 0.f);

#pragma unroll 1
  for (int c = 0; c < NC; ++c) {
    const int kb = c * 32;
    if (c) __syncthreads();
    // ---- stage A tile (64 nodes x 32 k) ----
#pragma unroll
    for (int it = 0; it < 2; ++it) {
      int idx = it * 256 + tid;
      int nl = idx >> 3;
      int kq = (idx & 7) * 4;
      int k = kb + kq;
      int ng = nbase + nl;
      float4 v = make_float4(0.f, 0.f, 0.f, 0.f);
      bool isA1 = (K2 == 0) || (k < K1);
      if (ng < N_NODES) {
        if (isA1)
          v = *reinterpret_cast<const float4*>(A1 + (size_t)ng * K1 + k);
        else
          v = *reinterpret_cast<const float4*>(A2 + (size_t)ng * K2 + (k - K1));
      }
      if constexpr (TA1) {
        if (isA1) {
          float4 s4 = *reinterpret_cast<const float4*>(sc + k);
          float4 h4 = *reinterpret_cast<const float4*>(sh + k);
          v.x = fmaxf(fmaf(v.x, s4.x, h4.x), 0.f);
          v.y = fmaxf(fmaf(v.y, s4.y, h4.y), 0.f);
          v.z = fmaxf(fmaf(v.z, s4.z, h4.z), 0.f);
          v.w = fmaxf(fmaf(v.w, s4.w, h4.w), 0.f);
          if (ng < N_NODES)
            *reinterpret_cast<float4*>(h2act + (size_t)ng * K1 + k) = v;
        }
      }
      if constexpr (TA2 && K2 > 0) {
        if (!isA1) {
          float4 s4 = *reinterpret_cast<const float4*>(sc + (k - K1));
          float4 h4 = *reinterpret_cast<const float4*>(sh + (k - K1));
          v.x = fmaxf(fmaf(v.x, s4.x, h4.x), 0.f);
          v.y = fmaxf(fmaf(v.y, s4.y, h4.y), 0.f);
          v.z = fmaxf(fmaf(v.z, s4.z, h4.z), 0.f);
          v.w = fmaxf(fmaf(v.w, s4.w, h4.w), 0.f);
        }
      }
      *reinterpret_cast<float4*>(&A_lds[nl][kq]) = v;
    }
    // ---- stage W chunk: linear float4 copy of 32 x DO ----
    {
      const float4* wsrc = reinterpret_cast<const float4*>(Wt + (size_t)kb * DO);
      float4* wdst = reinterpret_cast<float4*>(&W_lds[0][0]);
#pragma unroll
      for (int it = 0; it < DO / 32; ++it)
        wdst[it * 256 + tid] = wsrc[it * 256 + tid];
    }
    __syncthreads();
    // ---- compute (8 k4 steps of 4 k) ----
#pragma unroll 2
    for (int k4 = 0; k4 < 8; ++k4) {
      float4 a[4];
#pragma unroll
      for (int i = 0; i < 4; ++i)
        a[i] = *reinterpret_cast<const float4*>(&A_lds[ty * 4 + i][k4 * 4]);
#pragma unroll
      for (int q = 0; q < 4; ++q) {
#pragma unroll
        for (int jb = 0; jb < NJB; ++jb) {
          float4 w = *reinterpret_cast<const float4*>(&W_lds[k4 * 4 + q][jb * 64 + tx * 4]);
#pragma unroll
          for (int i = 0; i < 4; ++i) {
            float av = reinterpret_cast<const float*>(&a[i])[q];
            acc[i][jb].x = fmaf(av, w.x, acc[i][jb].x);
            acc[i][jb].y = fmaf(av, w.y, acc[i][jb].y);
            acc[i][jb].z = fmaf(av, w.z, acc[i][jb].z);
            acc[i][jb].w = fmaf(av, w.w, acc[i][jb].w);
          }
        }
      }
    }
  }
  // ---- R add + output ----
#pragma unroll
  for (int i = 0; i < 4; ++i) {
    int ng = nbase + ty * 4 + i;
    if (ng >= N_NODES) continue;
#pragma unroll
    for (int jb = 0; jb < NJB; ++jb) {
      if constexpr (RADD) {
        float4 rr = *reinterpret_cast<const float4*>(R + (size_t)ng * DO + jb * 64 + tx * 4);
        acc[i][jb].x += rr.x; acc[i][jb].y += rr.y;
        acc[i][jb].z += rr.z; acc[i][jb].w += rr.w;
      }
      size_t off = (size_t)ng * DO + jb * 64 + tx * 4;
      if constexpr (OUTM == 1) {
        ushort4 o = make_ushort4(f2bf(acc[i][jb].x), f2bf(acc[i][jb].y),
                                 f2bf(acc[i][jb].z), f2bf(acc[i][jb].w));
        *reinterpret_cast<ushort4*>((ushort*)out + off) = o;
      } else {
        *reinterpret_cast<float4*>(out + off) = acc[i][jb];
        if constexpr (OUTM == 2) {
          ushort4 o = make_ushort4(f2bf(acc[i][jb].x), f2bf(acc[i][jb].y),
                                   f2bf(acc[i][jb].z), f2bf(acc[i][jb].w));
          *reinterpret_cast<ushort4*>(outb + off) = o;
        }
      }
    }
  }
  // ---- fused BN stats ----
  if constexpr (STATS) {
    __syncthreads();
    float* sums_l = &A_lds[0][0];  // [16][DO] scratch (fits: 2304 >= 16*DO/ for DO<=128)
    float* sq_l = &W_lds[0][0];    // [16][DO]
#pragma unroll
    for (int jb = 0; jb < NJB; ++jb) {
      float4 s = make_float4(0.f, 0.f, 0.f, 0.f);
      float4 q = make_float4(0.f, 0.f, 0.f, 0.f);
#pragma unroll
      for (int i = 0; i < 4; ++i) {
        if (nbase + ty * 4 + i < N_NODES) {
          float4 v = acc[i][jb];
          s.x += v.x; s.y += v.y; s.z += v.z; s.w += v.w;
          q.x = fmaf(v.x, v.x, q.x); q.y = fmaf(v.y, v.y, q.y);
          q.z = fmaf(v.z, v.z, q.z); q.w = fmaf(v.w, v.w, q.w);
        }
      }
      *reinterpret_cast<float4*>(&sums_l[ty * DO + jb * 64 + tx * 4]) = s;
      *reinterpret_cast<float4*>(&sq_l[ty * DO + jb * 64 + tx * 4]) = q;
    }
    __syncthreads();
    if (tid < DO) {
      float s = 0.f, q = 0.f;
#pragma unroll
      for (int t = 0; t < 16; ++t) {
        s += sums_l[t * DO + tid];
        q += sq_l[t * DO + tid];
      }
      unsafeAtomicAdd(&sums[tid], s);
      unsafeAtomicAdd(&sums[DO + tid], q);
    }
  }
}

// ---------------- BN finalize ----------------

__global__ void bn_finalize(const float* __restrict__ sums, const float* __restrict__ g,
                            const float* __restrict__ be, float* __restrict__ sc,
                            float* __restrict__ sh, int D) {
  int j = threadIdx.x;
  if (j >= D) return;
  const float invN = 1.f / (float)N_NODES;
  float mean = sums[j] * invN;
  float var = sums[D + j] * invN - mean * mean;
  float r = rsqrtf(var + EPSV);
  float scale = g[j] * r;
  sc[j] = scale;
  sh[j] = be[j] - mean * scale;
}

// ---------------- fused residual + classifier ----------------

__global__ __launch_bounds__(256) void final_fused(
    const float* __restrict__ h3p, const float* __restrict__ h1p,
    const float* __restrict__ sc1, const float* __restrict__ sh1,
    const float* __restrict__ sc3, const float* __restrict__ sh3,
    const float* __restrict__ Wc1, const float* __restrict__ bc1,
    const float* __restrict__ Wc2, const float* __restrict__ bc2,
    float* __restrict__ out) {
  __shared__ __align__(16) float t_lds[64][68];
  __shared__ __align__(16) float w1_lds[64][36];
  __shared__ __align__(16) float c_lds[64][36];
  __shared__ __align__(16) float w2_lds[64];
  __shared__ __align__(16) float b1_lds[32];
  __shared__ float b2_lds[2];
  const int tid = threadIdx.x;
  const int nbase = blockIdx.x * 64;

#pragma unroll
  for (int it = 0; it < 4; ++it) {
    int idx = it * 256 + tid;
    int nl = idx >> 4;
    int k = (idx & 15) * 4;
    int ng = nbase + nl;
    float4 v = make_float4(0.f, 0.f, 0.f, 0.f);
    if (ng < N_NODES) {
      float4 p = *reinterpret_cast<const float4*>(h3p + (size_t)ng * 64 + k);
      float4 u = *reinterpret_cast<const float4*>(h1p + (size_t)ng * 64 + k);
      float4 sa = *reinterpret_cast<const float4*>(sc1 + k);
      float4 ha = *reinterpret_cast<const float4*>(sh1 + k);
      float4 sb = *reinterpret_cast<const float4*>(sc3 + k);
      float4 hb = *reinterpret_cast<const float4*>(sh3 + k);
      float h1x = fmaxf(fmaf(u.x, sa.x, ha.x), 0.f);
      float h1y = fmaxf(fmaf(u.y, sa.y, ha.y), 0.f);
      float h1z = fmaxf(fmaf(u.z, sa.z, ha.z), 0.f);
      float h1w = fmaxf(fmaf(u.w, sa.w, ha.w), 0.f);
      v.x = fmaxf(fmaf(p.x, sb.x, hb.x) + h1x, 0.f);
      v.y = fmaxf(fmaf(p.y, sb.y, hb.y) + h1y, 0.f);
      v.z = fmaxf(fmaf(p.z, sb.z, hb.z) + h1z, 0.f);
      v.w = fmaxf(fmaf(p.w, sb.w, hb.w) + h1w, 0.f);
    }
    *reinterpret_cast<float4*>(&t_lds[nl][k]) = v;
  }
#pragma unroll
  for (int it = 0; it < 8; ++it) {
    int idx = it * 256 + tid;
    int j = idx >> 6;
    int k = idx & 63;
    w1_lds[k][j] = Wc1[(size_t)j * 64 + k];
  }
  if (tid < 64) w2_lds[tid] = Wc2[tid];
  else if (tid < 96) b1_lds[tid - 64] = bc1[tid - 64];
  else if (tid < 98) b2_lds[tid - 96] = bc2[tid - 96];
  __syncthreads();

  {
    const int tx = tid & 7, ty = tid >> 3;
    float4 a0c = make_float4(0.f, 0.f, 0.f, 0.f);
    float4 a1c = make_float4(0.f, 0.f, 0.f, 0.f);
#pragma unroll 4
    for (int k4 = 0; k4 < 16; ++k4) {
      float4 a0 = *reinterpret_cast<const float4*>(&t_lds[ty * 2 + 0][k4 * 4]);
      float4 a1 = *reinterpret_cast<const float4*>(&t_lds[ty * 2 + 1][k4 * 4]);
#pragma unroll
      for (int q = 0; q < 4; ++q) {
        float4 w = *reinterpret_cast<const float4*>(&w1_lds[k4 * 4 + q][tx * 4]);
        float a0q = reinterpret_cast<const float*>(&a0)[q];
        float a1q = reinterpret_cast<const float*>(&a1)[q];
        a0c.x = fmaf(a0q, w.x, a0c.x); a0c.y = fmaf(a0q, w.y, a0c.y);
        a0c.z = fmaf(a0q, w.z, a0c.z); a0c.w = fmaf(a0q, w.w, a0c.w);
        a1c.x = fmaf(a1q, w.x, a1c.x); a1c.y = fmaf(a1q, w.y, a1c.y);
        a1c.z = fmaf(a1q, w.z, a1c.z); a1c.w = fmaf(a1q, w.w, a1c.w);
      }
    }
    float4 b = *reinterpret_cast<const float4*>(&b1_lds[tx * 4]);
    a0c.x = fmaxf(a0c.x + b.x, 0.f); a0c.y = fmaxf(a0c.y + b.y, 0.f);
    a0c.z = fmaxf(a0c.z + b.z, 0.f); a0c.w = fmaxf(a0c.w + b.w, 0.f);
    a1c.x = fmaxf(a1c.x + b.x, 0.f); a1c.y = fmaxf(a1c.y + b.y, 0.f);
    a1c.z = fmaxf(a1c.z + b.z, 0.f); a1c.w = fmaxf(a1c.w + b.w, 0.f);
    *reinterpret_cast<float4*>(&c_lds[ty * 2 + 0][tx * 4]) = a0c;
    *reinterpret_cast<float4*>(&c_lds[ty * 2 + 1][tx * 4]) = a1c;
  }
  __syncthreads();

  if (tid < 128) {
    int nl = tid >> 1, o = tid & 1;
    int ng = nbase + nl;
    if (ng < N_NODES) {
      float s = b2_lds[o];
#pragma unroll
      for (int k = 0; k < 32; ++k) s = fmaf(c_lds[nl][k], w2_lds[o * 32 + k], s);
      out[(size_t)ng * 2 + o] = s;
    }
  }
}

// ---------------- launcher ----------------

extern "C" void kernel_launch(void* const* d_in, const int* in_sizes, int n_in,
                              void* d_out, int out_size, void* d_ws, size_t ws_size,
                              hipStream_t stream) {
  const float* x      = (const float*)d_in[0];
  const int*   ei     = (const int*)d_in[1];
  const float* ew     = (const float*)d_in[2];
  const float* W1rel  = (const float*)d_in[3];
  const float* W1root = (const float*)d_in[5];
  const float* W2rel  = (const float*)d_in[6];
  const float* W2root = (const float*)d_in[8];
  const float* W3rel  = (const float*)d_in[9];
  const float* W3root = (const float*)d_in[11];
  const float* g1  = (const float*)d_in[12];
  const float* be1 = (const float*)d_in[13];
  const float* g2  = (const float*)d_in[14];
  const float* be2 = (const float*)d_in[15];
  const float* g3  = (const float*)d_in[16];
  const float* be3 = (const float*)d_in[17];
  const float* Wc1 = (const float*)d_in[18];
  const float* bc1 = (const float*)d_in[19];
  const float* Wc2 = (const float*)d_in[20];
  const float* bc2 = (const float*)d_in[21];

  float* ws = (float*)d_ws;
  const size_t NF = (size_t)N_NODES * 64;
  float* A = ws;            // agg1 (N*32) -> agg2 (N*64) -> agg3 (N*64)
  float* B = ws + NF;       // xb(bf16) -> y2b(bf16) -> h3pre(fp32)
  float* C = ws + 2 * NF;   // h1pre fp32, live to the end
  float* E = ws + 3 * NF;   // h1preb(bf16) -> h2pre/h2act fp32 (N*128)
  float* X = ws + 5 * NF;
  float* S = X;                                 // 1024 floats: sums + sc/sh slots
  int* rowptr   = (int*)(X + 1024);             // N+2
  int* cnt      = rowptr + (N_NODES + 2);       // N
  int* cursor   = cnt + N_NODES;                // N
  int* blocksum = cursor + N_NODES;             // 128
  unsigned* col = (unsigned*)(blocksum + 128);  // E packed (w15|src17), 4B
  float* Wt     = (float*)(col + N_EDGES);      // 36864 floats, pre-transposed weights
  // S: sums1@0(128) sc1@128 sh1@192 | sums2@256(256) sc2@512 sh2@640 |
  //    sums3@768(128) sc3@896 sh3@960
  float* Wt1  = Wt;
  float* Wt2  = Wt + 4096;
  float* Wt3r = Wt + 20480;
  float* Wt3o = Wt + 28672;

  ushort* xb     = (ushort*)B;  // N*32 bf16, dead after gather1
  ushort* h1preb = (ushort*)E;  // N*64 bf16, dead after gather2
  ushort* y2b    = (ushort*)B;  // N*64 bf16, dead after gather3

  hipMemsetAsync(S, 0, 1024 * sizeof(float), stream);
  hipMemsetAsync(cnt, 0, N_NODES * sizeof(int), stream);

  const int edgeBlocks = (N_EDGES + 255) / 256;
  const int tileBlocks = (N_NODES + 63) / 64;  // 1563

  // independent prep
  cast_bf16<<<(N_NODES * 32 / 4 + 255) / 256, 256, 0, stream>>>(x, xb, N_NODES * 32 / 4);
  wtrans_kernel<<<144, 256, 0, stream>>>(W1rel, W1root, W2rel, W2root, W3rel, W3root, Wt);

  // CSR build (by destination)
  hist_kernel<<<edgeBlocks, 256, 0, stream>>>(ei, cnt);
  scan_phase1<<<SCAN_NB, 256, 0, stream>>>(cnt, blocksum);
  scan_phase2<<<1, 128, 0, stream>>>(blocksum, rowptr);
  scan_phase3<<<SCAN_NB, 256, 0, stream>>>(cnt, blocksum, rowptr, cursor);
  fill_kernel<<<8 * FILL_SUB, 256, 0, stream>>>(ei, ew, cursor, col);

  // ---- layer 1 ----
  gather_d32_bf<<<(N_NODES * 4 + 255) / 256, 256, 0, stream>>>(xb, rowptr, col, A);
  gemm_node<32, 32, 64, 0, 0, 0, 1, 2><<<tileBlocks, 256, 0, stream>>>(
      A, x, Wt1, nullptr, nullptr, nullptr, C, h1preb, nullptr, S);
  bn_finalize<<<1, 128, 0, stream>>>(S, g1, be1, S + 128, S + 192, 64);

  // ---- layer 2 (BN1+relu fused into gather and gemm2 staging) ----
  gather_d64_bf<false, true><<<(N_NODES * 8 + 255) / 256, 256, 0, stream>>>(
      h1preb, rowptr, col, S + 128, S + 192, A);
  gemm_node<64, 64, 128, 0, 1, 0, 1, 0><<<tileBlocks, 256, 0, stream>>>(
      A, C, Wt2, S + 128, S + 192, nullptr, E, nullptr, nullptr, S + 256);
  bn_finalize<<<1, 128, 0, stream>>>(S + 256, g2, be2, S + 512, S + 640, 128);

  // y2b = bf16( relu(bn2(h2pre)) @ W3rel^T ); h2act -> E in place
  gemm_node<128, 0, 64, 1, 0, 0, 0, 1><<<tileBlocks, 256, 0, stream>>>(
      E, nullptr, Wt3r, S + 512, S + 640, nullptr, (float*)y2b, nullptr, E, nullptr);

  // ---- layer 3 ----
  gather_d64_bf<true, false><<<(N_NODES * 8 + 255) / 256, 256, 0, stream>>>(
      y2b, rowptr, col, nullptr, nullptr, A);
  gemm_node<128, 0, 64, 0, 0, 1, 1, 0><<<tileBlocks, 256, 0, stream>>>(
      E, nullptr, Wt3o, nullptr, nullptr, A, B, nullptr, nullptr, S + 768);
  bn_finalize<<<1, 128, 0, stream>>>(S + 768, g3, be3, S + 896, S + 960, 64);

  // ---- residual + classifier ----
  final_fused<<<tileBlocks, 256, 0, stream>>>(B, C, S + 128, S + 192, S + 896, S + 960,
                                              Wc1, bc1, Wc2, bc2, (float*)d_out);
}